// Round 7
// baseline (3444.350 us; speedup 1.0000x reference)
//
#include <hip/hip_runtime.h>
#include <cstdint>

// ---------------------------------------------------------------------------
// Autoformer forward — hybrid precision v12 (R17):
//   * R17: gemm_hf REVERTED (A-f32 staging = 2x LDS bytes + 32 cvt on the
//     LDS->MFMA critical path; 51us vs ~40 for acvt+fp16 path). FFN1 back
//     to acvt_k -> Ph (v8-proven). gemm_h rebuilt at BK=32 with R16's
//     2-phase double-buffered K-loop (gemm_z's verified staging geometry;
//     LDS stays 32KB so occupancy unchanged) — now V / Wo / FFN1 / FFN2
//     all get the prefetch-before-compute schedule.
//   * R16: 2-phase K-loop in gemm_z / qkmv_hl (verified −183us).
//   * R15: XCD-aware bijective block swizzle (FETCH 67.8->24.8 MB).
//   * R14a: conv_embed register-caches xs columns.
//   * R13: proj1 read-once split-K; colmean partials.
//   * R11: tsplit2_k + split-fp16 MFMA gemm_z @ 512^3 for G.
// Inputs f32 (runtime-detected from x_mark_enc; bf16 fallback kept).
//
// Workspace (bytes), total ~148.1 MB:
//   X    @ 0          : f32 residual 64Mi; FFN: Hb fp16 hidden (0..32Mi)
//   XH   @ 67108864   : fp16 X-high 32Mi | FFN: S2 f32 64Mi (spans XH+XL!)
//   XL   @ 100663296  : fp16 X-low*512 32Mi / AGh   (S2 second half!)
//   ZH   @ 134217728  : fp16 Z-high chunk 4Mi \ Ph 8Mi (V chunk / FFN in)
//   ZL   @ 138412032  : fp16 Z-low chunk 4Mi  /  | final: CMp
//   SH   @ 142606336  : Phase A: wT | KTH/KTL/QTH/QTL + GH/GL
//                       Phase B: Wvh/Woh/W1h/W2h
//   MV   @ 147849216, WGT @ 147980288, DLY @ 147981312, FLAG @ 148068352
//   PB2  @ 67108864 (over S2, dead at proj time)
// ---------------------------------------------------------------------------

using u16 = unsigned short;
typedef _Float16 f16x8 __attribute__((ext_vector_type(8)));
typedef float f32x4 __attribute__((ext_vector_type(4)));

#define BB 32
#define LL 1024
#define DD 512
#define DFF 2048

__device__ __forceinline__ float bf2f(u16 u) {
  union { uint32_t i; float f; } v; v.i = ((uint32_t)u) << 16; return v.f;
}
__device__ __forceinline__ u16 f2bf(float f) {
  union { float f; uint32_t i; } v; v.f = f;
  uint32_t r = (v.i + 0x7FFFu + ((v.i >> 16) & 1u)) >> 16;
  return (u16)r;
}
__device__ __forceinline__ float ldi(const void* p, long i, int isf) {
  return isf ? ((const float*)p)[i] : bf2f(((const u16*)p)[i]);
}
__device__ __forceinline__ float gelu_f(float x) {
  return 0.5f * x * (1.0f + erff(x * 0.70710678118654752440f));
}
// async 16B global -> LDS (wave-uniform LDS base + lane*16)
__device__ __forceinline__ void gld16(const void* g, void* l) {
  __builtin_amdgcn_global_load_lds(
      (const __attribute__((address_space(1))) void*)g,
      (__attribute__((address_space(3))) void*)l, 16, 0, 0);
}
// XCD-aware bijective block swizzle (requires nwg % 8 == 0, all grids comply)
__device__ __forceinline__ void swz8(int& bx, int& by) {
  int gx = gridDim.x;
  int nwg = gx * gridDim.y;
  int bid = by * gx + bx;
  int q = nwg >> 3;
  int s = (bid & 7) * q + (bid >> 3);
  bx = s % gx;
  by = s / gx;
}

union H8 { f16x8 v; uint4 u; _Float16 h[8]; };
union H4 { uint2 u; _Float16 h[4]; };

__global__ void detect_k(const uint32_t* __restrict__ mark, int* __restrict__ FLAG) {
  if (threadIdx.x == 0) FLAG[0] = (mark[0] == 0x3F800000u) ? 1 : 0;
}

// transpose conv weight to wT[(c*3+t)*512 + d], f32. grid 126, block 256
__global__ __launch_bounds__(256) void wT_k(const void* __restrict__ w,
                                            float* __restrict__ wT,
                                            const int* __restrict__ FLAG) {
  const int isf = *FLAG;
  int idx = blockIdx.x * 256 + threadIdx.x;
  if (idx >= 63 * DD) return;
  int c3t = idx / DD;
  int d = idx - c3t * DD;
  wT[idx] = ldi(w, (long)d * 63 + c3t, isf);
}

// ---------------------------------------------------------------------------
// Conv1d circular embedding + fused split. grid (L/16, B), block 256.
// ---------------------------------------------------------------------------
__global__ __launch_bounds__(256) void conv_embed_k(
    const void* __restrict__ xe, const float* __restrict__ wT,
    float* __restrict__ X, _Float16* __restrict__ XH, _Float16* __restrict__ XL,
    const int* __restrict__ FLAG) {
  const int isf = *FLAG;
  int b = blockIdx.y;
  int l0 = blockIdx.x * 16;
  __shared__ float xs[18][21];
  int tid = threadIdx.x;
  for (int i = tid; i < 18 * 21; i += 256) {
    int r = i / 21, c = i % 21;
    int row = (l0 - 1 + r + LL) & (LL - 1);
    xs[r][c] = ldi(xe, ((long)b * LL + row) * 21 + c, isf);
  }
  __syncthreads();
  float acc0[16], acc1[16];
#pragma unroll
  for (int ll = 0; ll < 16; ll++) { acc0[ll] = 0.0f; acc1[ll] = 0.0f; }
  for (int c = 0; c < 21; c++) {
    float xreg[18];
#pragma unroll
    for (int r = 0; r < 18; r++) xreg[r] = xs[r][c];
#pragma unroll
    for (int t = 0; t < 3; t++) {
      float w0 = wT[(c * 3 + t) * DD + tid];
      float w1 = wT[(c * 3 + t) * DD + tid + 256];
#pragma unroll
      for (int ll = 0; ll < 16; ll++) {
        acc0[ll] = fmaf(w0, xreg[t + ll], acc0[ll]);
        acc1[ll] = fmaf(w1, xreg[t + ll], acc1[ll]);
      }
    }
  }
#pragma unroll
  for (int ll = 0; ll < 16; ll++) {
    long base = ((long)b * LL + l0 + ll) * DD;
    float v0 = acc0[ll], v1 = acc1[ll];
    X[base + tid] = v0;
    X[base + tid + 256] = v1;
    _Float16 h0 = (_Float16)v0, h1 = (_Float16)v1;
    XH[base + tid] = h0;
    XH[base + tid + 256] = h1;
    XL[base + tid] = (_Float16)((v0 - (float)h0) * 512.0f);
    XL[base + tid + 256] = (_Float16)((v1 - (float)h1) * 512.0f);
  }
}

// ---------------------------------------------------------------------------
// transpose + split BOTH Wq/Wk in one launch. grid (8, 8, 2), block 256.
// ---------------------------------------------------------------------------
__global__ __launch_bounds__(256) void tsplit2_k(
    const void* __restrict__ W1, const void* __restrict__ W2, long off,
    _Float16* __restrict__ T1H, _Float16* __restrict__ T1L,
    _Float16* __restrict__ T2H, _Float16* __restrict__ T2L,
    const int* __restrict__ FLAG) {
  const int isf = *FLAG;
  const void* W = blockIdx.z ? W2 : W1;
  _Float16* TH = blockIdx.z ? T2H : T1H;
  _Float16* TL = blockIdx.z ? T2L : T1L;
  __shared__ float t[64][65];
  const int f0 = blockIdx.x * 64, m0 = blockIdx.y * 64;
  const int tid = threadIdx.x;
  const int c = tid & 63, rb = tid >> 6;
#pragma unroll
  for (int r = rb; r < 64; r += 4)
    t[r][c] = ldi(W, off + (long)(f0 + r) * DD + m0 + c, isf);
  __syncthreads();
#pragma unroll
  for (int r = rb; r < 64; r += 4) {
    float v = t[c][r];
    long o = (long)(m0 + r) * DD + f0 + c;
    _Float16 hv = (_Float16)v;
    TH[o] = hv;
    TL[o] = (_Float16)((v - (float)hv) * 512.0f);
  }
}

// split f32 -> (fp16 high, fp16 low*512). 8 elems/thread.
__global__ __launch_bounds__(256) void split_k(const float* __restrict__ src,
                                               _Float16* __restrict__ dh,
                                               _Float16* __restrict__ dl, int n) {
  long i = ((long)blockIdx.x * 256 + threadIdx.x) * 8;
  if (i >= n) return;
  float4 a = *(const float4*)(src + i);
  float4 b = *(const float4*)(src + i + 4);
  float x[8] = {a.x, a.y, a.z, a.w, b.x, b.y, b.z, b.w};
  H8 h, l;
#pragma unroll
  for (int j = 0; j < 8; j++) {
    _Float16 hv = (_Float16)x[j];
    h.h[j] = hv;
    l.h[j] = (_Float16)((x[j] - (float)hv) * 512.0f);
  }
  *(uint4*)(dh + i) = h.u;
  *(uint4*)(dl + i) = l.u;
}

// convert f32 -> fp16 (plain), 8 elems/thread
__global__ __launch_bounds__(256) void acvt_k(const float* __restrict__ src,
                                              _Float16* __restrict__ dst, int n) {
  long i = ((long)blockIdx.x * 256 + threadIdx.x) * 8;
  if (i >= n) return;
  float4 a = *(const float4*)(src + i);
  float4 b = *(const float4*)(src + i + 4);
  H8 r;
  r.h[0] = (_Float16)a.x; r.h[1] = (_Float16)a.y;
  r.h[2] = (_Float16)a.z; r.h[3] = (_Float16)a.w;
  r.h[4] = (_Float16)b.x; r.h[5] = (_Float16)b.y;
  r.h[6] = (_Float16)b.z; r.h[7] = (_Float16)b.w;
  *(uint4*)(dst + i) = r.u;
}

// all four Phase-B weights -> fp16 in one launch. grid 1280, block 256
__global__ __launch_bounds__(256) void wcvt6_k(
    const void* __restrict__ Wv, const void* __restrict__ Wo,
    const void* __restrict__ W1, const void* __restrict__ W2,
    long oW, long oF,
    _Float16* __restrict__ Wvh, _Float16* __restrict__ Woh,
    _Float16* __restrict__ W1h, _Float16* __restrict__ W2h,
    const int* __restrict__ FLAG) {
  const int isf = *FLAG;
  long e = ((long)blockIdx.x * 256 + threadIdx.x) * 8;
  const void* src; long soff; _Float16* dst;
  if (e < 262144) { src = Wv; soff = oW + e; dst = Wvh + e; }
  else if (e < 524288) { src = Wo; soff = oW + (e - 262144); dst = Woh + (e - 262144); }
  else if (e < 1572864) { src = W1; soff = oF + (e - 524288); dst = W1h + (e - 524288); }
  else { src = W2; soff = oF + (e - 1572864); dst = W2h + (e - 1572864); }
  H8 r;
  if (isf) {
    const float* s = (const float*)src + soff;
    float4 a = *(const float4*)s;
    float4 b = *(const float4*)(s + 4);
    r.h[0] = (_Float16)a.x; r.h[1] = (_Float16)a.y;
    r.h[2] = (_Float16)a.z; r.h[3] = (_Float16)a.w;
    r.h[4] = (_Float16)b.x; r.h[5] = (_Float16)b.y;
    r.h[6] = (_Float16)b.z; r.h[7] = (_Float16)b.w;
  } else {
    const u16* s = (const u16*)src + soff;
    uint4 u = *(const uint4*)s;
    r.h[0] = (_Float16)bf2f((u16)(u.x & 0xffff));
    r.h[1] = (_Float16)bf2f((u16)(u.x >> 16));
    r.h[2] = (_Float16)bf2f((u16)(u.y & 0xffff));
    r.h[3] = (_Float16)bf2f((u16)(u.y >> 16));
    r.h[4] = (_Float16)bf2f((u16)(u.z & 0xffff));
    r.h[5] = (_Float16)bf2f((u16)(u.z >> 16));
    r.h[6] = (_Float16)bf2f((u16)(u.w & 0xffff));
    r.h[7] = (_Float16)bf2f((u16)(u.w >> 16));
  }
  *(uint4*)(dst) = r.u;
}

// ---------------------------------------------------------------------------
// split-fp16 MFMA GEMM: Z = A @ W^T (split in/out). BK=32.
// R16: 2-phase double-buffered (verified).
// ---------------------------------------------------------------------------
__global__ __launch_bounds__(256) void gemm_z(
    const _Float16* __restrict__ Ah, const _Float16* __restrict__ Al,
    const _Float16* __restrict__ Bh, const _Float16* __restrict__ Bl,
    _Float16* __restrict__ Zh, _Float16* __restrict__ Zl,
    int M, int N, int K) {
  __shared__ __align__(16) _Float16 AsH[2][128 * 32];
  __shared__ __align__(16) _Float16 AsL[2][128 * 32];
  __shared__ __align__(16) _Float16 BsH[2][128 * 32];
  __shared__ __align__(16) _Float16 BsL[2][128 * 32];
  int bx = blockIdx.x, by = blockIdx.y;
  swz8(bx, by);
  const int n0 = bx * 128, m0 = by * 128;
  const int tid = threadIdx.x;
  const int lane = tid & 63, wvi = tid >> 6;
  const int wm = (wvi >> 1) * 64, wn = (wvi & 1) * 64;
  const int l15 = lane & 15, quad = lane >> 4;
  const int ib = wvi * 128 + lane;
  const int r0 = ib >> 2, r1 = r0 + 16;
  const int c0 = ((ib & 3) ^ ((r0 >> 1) & 3)) * 8;
  const int c1 = ((ib & 3) ^ ((r1 >> 1) & 3)) * 8;
  const int lb0 = wvi * 1024, lb1 = wvi * 1024 + 512;
  const long ga0 = (long)(m0 + r0) * K + c0;
  const long ga1 = (long)(m0 + r1) * K + c1;
  const long gb0 = (long)(n0 + r0) * K + c0;
  const long gb1 = (long)(n0 + r1) * K + c1;
  f32x4 aM[4][4], aC[4][4];
#pragma unroll
  for (int i = 0; i < 4; i++)
#pragma unroll
    for (int j = 0; j < 4; j++) {
      aM[i][j] = (f32x4){0.f, 0.f, 0.f, 0.f};
      aC[i][j] = (f32x4){0.f, 0.f, 0.f, 0.f};
    }
  // prologue: stage tile 0 into buffer 0
  gld16(Ah + ga0, AsH[0] + lb0);
  gld16(Ah + ga1, AsH[0] + lb1);
  gld16(Al + ga0, AsL[0] + lb0);
  gld16(Al + ga1, AsL[0] + lb1);
  gld16(Bh + gb0, BsH[0] + lb0);
  gld16(Bh + gb1, BsH[0] + lb1);
  gld16(Bl + gb0, BsL[0] + lb0);
  gld16(Bl + gb1, BsL[0] + lb1);
  __syncthreads();
  int cur = 0;
  for (int k0 = 0; k0 < K; k0 += 32) {
    const int kn = k0 + 32;
    if (kn < K) {  // prefetch next tile into the other buffer
      gld16(Ah + ga0 + kn, AsH[cur ^ 1] + lb0);
      gld16(Ah + ga1 + kn, AsH[cur ^ 1] + lb1);
      gld16(Al + ga0 + kn, AsL[cur ^ 1] + lb0);
      gld16(Al + ga1 + kn, AsL[cur ^ 1] + lb1);
      gld16(Bh + gb0 + kn, BsH[cur ^ 1] + lb0);
      gld16(Bh + gb1 + kn, BsH[cur ^ 1] + lb1);
      gld16(Bl + gb0 + kn, BsL[cur ^ 1] + lb0);
      gld16(Bl + gb1 + kn, BsL[cur ^ 1] + lb1);
    }
    f16x8 fah[4], fal[4], fbh[4], fbl[4];
#pragma unroll
    for (int mi = 0; mi < 4; mi++) {
      int r = wm + mi * 16 + l15;
      int o = r * 32 + ((quad ^ ((r >> 1) & 3)) * 8);
      fah[mi] = *(const f16x8*)&AsH[cur][o];
      fal[mi] = *(const f16x8*)&AsL[cur][o];
    }
#pragma unroll
    for (int ni = 0; ni < 4; ni++) {
      int r = wn + ni * 16 + l15;
      int o = r * 32 + ((quad ^ ((r >> 1) & 3)) * 8);
      fbh[ni] = *(const f16x8*)&BsH[cur][o];
      fbl[ni] = *(const f16x8*)&BsL[cur][o];
    }
#pragma unroll
    for (int mi = 0; mi < 4; mi++)
#pragma unroll
      for (int ni = 0; ni < 4; ni++) {
        aM[mi][ni] = __builtin_amdgcn_mfma_f32_16x16x32_f16(
            fah[mi], fbh[ni], aM[mi][ni], 0, 0, 0);
        aC[mi][ni] = __builtin_amdgcn_mfma_f32_16x16x32_f16(
            fah[mi], fbl[ni], aC[mi][ni], 0, 0, 0);
        aC[mi][ni] = __builtin_amdgcn_mfma_f32_16x16x32_f16(
            fal[mi], fbh[ni], aC[mi][ni], 0, 0, 0);
      }
    __syncthreads();  // drains prefetch (vmcnt 0) + guards buffer reuse
    cur ^= 1;
  }
#pragma unroll
  for (int mi = 0; mi < 4; mi++) {
    int rowg = m0 + wm + mi * 16 + quad * 4;
#pragma unroll
    for (int ni = 0; ni < 4; ni++) {
      int colg = n0 + wn + ni * 16 + l15;
#pragma unroll
      for (int rr = 0; rr < 4; rr++) {
        long off = (long)(rowg + rr) * N + colg;
        float z = aM[mi][ni][rr] + aC[mi][ni][rr] * (1.0f / 512.0f);
        _Float16 zh = (_Float16)z;
        Zh[off] = zh;
        Zl[off] = (_Float16)((z - (float)zh) * 512.0f);
      }
    }
  }
}

// ---------------------------------------------------------------------------
// split-fp16 MFMA Z.X^T + fused wrapped-diagonal mean reduce. BK=32.
// R16: 2-phase double-buffered (verified).
// ---------------------------------------------------------------------------
__global__ __launch_bounds__(256) void qkmv_hl(
    const _Float16* __restrict__ Zh, const _Float16* __restrict__ Zl,
    const _Float16* __restrict__ Xh, const _Float16* __restrict__ Xl,
    float* __restrict__ MV) {
  __shared__ __align__(16) _Float16 AsH[2][128 * 32];
  __shared__ __align__(16) _Float16 AsL[2][128 * 32];
  __shared__ __align__(16) _Float16 BsH[2][128 * 32];
  __shared__ __align__(16) _Float16 BsL[2][128 * 32];
  __shared__ float diag[255];
  const int bz = blockIdx.z;
  const long bb = (long)bz * LL * DD;
  const int n0 = blockIdx.x * 128, m0 = blockIdx.y * 128;
  const int tid = threadIdx.x;
  const int lane = tid & 63, wvi = tid >> 6;
  const int wm = (wvi >> 1) * 64, wn = (wvi & 1) * 64;
  const int l15 = lane & 15, quad = lane >> 4;
  const int ib = wvi * 128 + lane;
  const int r0 = ib >> 2, r1 = r0 + 16;
  const int c0 = ((ib & 3) ^ ((r0 >> 1) & 3)) * 8;
  const int c1 = ((ib & 3) ^ ((r1 >> 1) & 3)) * 8;
  const int lb0 = wvi * 1024, lb1 = wvi * 1024 + 512;
  const long ga0 = bb + (long)(m0 + r0) * DD + c0;
  const long ga1 = bb + (long)(m0 + r1) * DD + c1;
  const long gb0 = bb + (long)(n0 + r0) * DD + c0;
  const long gb1 = bb + (long)(n0 + r1) * DD + c1;
  if (tid < 255) diag[tid] = 0.0f;
  f32x4 aM[4][4], aC[4][4];
#pragma unroll
  for (int i = 0; i < 4; i++)
#pragma unroll
    for (int j = 0; j < 4; j++) {
      aM[i][j] = (f32x4){0.f, 0.f, 0.f, 0.f};
      aC[i][j] = (f32x4){0.f, 0.f, 0.f, 0.f};
    }
  // prologue
  gld16(Zh + ga0, AsH[0] + lb0);
  gld16(Zh + ga1, AsH[0] + lb1);
  gld16(Zl + ga0, AsL[0] + lb0);
  gld16(Zl + ga1, AsL[0] + lb1);
  gld16(Xh + gb0, BsH[0] + lb0);
  gld16(Xh + gb1, BsH[0] + lb1);
  gld16(Xl + gb0, BsL[0] + lb0);
  gld16(Xl + gb1, BsL[0] + lb1);
  __syncthreads();
  int cur = 0;
  for (int k0 = 0; k0 < DD; k0 += 32) {
    const int kn = k0 + 32;
    if (kn < DD) {
      gld16(Zh + ga0 + kn, AsH[cur ^ 1] + lb0);
      gld16(Zh + ga1 + kn, AsH[cur ^ 1] + lb1);
      gld16(Zl + ga0 + kn, AsL[cur ^ 1] + lb0);
      gld16(Zl + ga1 + kn, AsL[cur ^ 1] + lb1);
      gld16(Xh + gb0 + kn, BsH[cur ^ 1] + lb0);
      gld16(Xh + gb1 + kn, BsH[cur ^ 1] + lb1);
      gld16(Xl + gb0 + kn, BsL[cur ^ 1] + lb0);
      gld16(Xl + gb1 + kn, BsL[cur ^ 1] + lb1);
    }
    f16x8 fah[4], fal[4], fbh[4], fbl[4];
#pragma unroll
    for (int mi = 0; mi < 4; mi++) {
      int r = wm + mi * 16 + l15;
      int o = r * 32 + ((quad ^ ((r >> 1) & 3)) * 8);
      fah[mi] = *(const f16x8*)&AsH[cur][o];
      fal[mi] = *(const f16x8*)&AsL[cur][o];
    }
#pragma unroll
    for (int ni = 0; ni < 4; ni++) {
      int r = wn + ni * 16 + l15;
      int o = r * 32 + ((quad ^ ((r >> 1) & 3)) * 8);
      fbh[ni] = *(const f16x8*)&BsH[cur][o];
      fbl[ni] = *(const f16x8*)&BsL[cur][o];
    }
#pragma unroll
    for (int mi = 0; mi < 4; mi++)
#pragma unroll
      for (int ni = 0; ni < 4; ni++) {
        aM[mi][ni] = __builtin_amdgcn_mfma_f32_16x16x32_f16(
            fah[mi], fbh[ni], aM[mi][ni], 0, 0, 0);
        aC[mi][ni] = __builtin_amdgcn_mfma_f32_16x16x32_f16(
            fah[mi], fbl[ni], aC[mi][ni], 0, 0, 0);
        aC[mi][ni] = __builtin_amdgcn_mfma_f32_16x16x32_f16(
            fal[mi], fbh[ni], aC[mi][ni], 0, 0, 0);
      }
    __syncthreads();
    cur ^= 1;
  }
#pragma unroll
  for (int g = -3; g <= 3; g++) {
#pragma unroll
    for (int rr = 0; rr < 4; rr++) {
      float s = 0.0f;
#pragma unroll
      for (int mi = 0; mi < 4; mi++) {
        int ni = mi - g;
        if (ni >= 0 && ni < 4)
          s += aM[mi][ni][rr] + aC[mi][ni][rr] * (1.0f / 512.0f);
      }
      int d = 127 + (wm - wn) + g * 16 + quad * 4 + rr - l15;
      atomicAdd(&diag[d], s);
    }
  }
  __syncthreads();
  if (tid < 255) {
    int tau = (m0 - n0 + tid - 127 + LL) & (LL - 1);
    atomicAdd(&MV[(long)bz * LL + tau], diag[tid] * (1.0f / 512.0f));
  }
}

// ---------------------------------------------------------------------------
// fp16 MFMA GEMM: C[M,N] = act( A[M,K] @ W[N,K]^T + bias + R )
// R17: BK=32, 2-phase double-buffered (gemm_z's verified staging geometry).
// LDS 32KB (2 buf x (8KB A + 8KB B)) — occupancy unchanged vs old BK=64.
// FLAGS: 1=bias 2=gelu 4=residual 8=out-fp16
// ---------------------------------------------------------------------------
template <int FLAGS>
__global__ __launch_bounds__(256) void gemm_h(
    const _Float16* __restrict__ A, const _Float16* __restrict__ W,
    const void* __restrict__ biasBase, long bOff,
    const float* __restrict__ R, void* __restrict__ Cout,
    int M, int N, int K, const int* __restrict__ FLAG) {
  constexpr bool HAS_BIAS = (FLAGS & 1) != 0;
  constexpr bool DO_GELU = (FLAGS & 2) != 0;
  constexpr bool DO_RES = (FLAGS & 4) != 0;
  constexpr bool OUT_H = (FLAGS & 8) != 0;
  __shared__ __align__(16) _Float16 As[2][128 * 32];
  __shared__ __align__(16) _Float16 Bs[2][128 * 32];
  int bx = blockIdx.x, by = blockIdx.y;
  swz8(bx, by);
  const int n0 = bx * 128, m0 = by * 128;
  const int tid = threadIdx.x;
  const int lane = tid & 63, wvi = tid >> 6;
  const int wm = (wvi >> 1) * 64, wn = (wvi & 1) * 64;
  const int l15 = lane & 15, quad = lane >> 4;
  const int ib = wvi * 128 + lane;
  const int r0 = ib >> 2, r1 = r0 + 16;
  const int c0 = ((ib & 3) ^ ((r0 >> 1) & 3)) * 8;
  const int c1 = ((ib & 3) ^ ((r1 >> 1) & 3)) * 8;
  const int lb0 = wvi * 1024, lb1 = wvi * 1024 + 512;
  const long ga0 = (long)(m0 + r0) * K + c0;
  const long ga1 = (long)(m0 + r1) * K + c1;
  const long gb0 = (long)(n0 + r0) * K + c0;
  const long gb1 = (long)(n0 + r1) * K + c1;
  f32x4 acc[4][4];
#pragma unroll
  for (int i = 0; i < 4; i++)
#pragma unroll
    for (int j = 0; j < 4; j++) acc[i][j] = (f32x4){0.f, 0.f, 0.f, 0.f};
  // prologue: stage tile 0 into buffer 0
  gld16(A + ga0, As[0] + lb0);
  gld16(A + ga1, As[0] + lb1);
  gld16(W + gb0, Bs[0] + lb0);
  gld16(W + gb1, Bs[0] + lb1);
  __syncthreads();
  int cur = 0;
  for (int k0 = 0; k0 < K; k0 += 32) {
    const int kn = k0 + 32;
    if (kn < K) {  // prefetch next tile
      gld16(A + ga0 + kn, As[cur ^ 1] + lb0);
      gld16(A + ga1 + kn, As[cur ^ 1] + lb1);
      gld16(W + gb0 + kn, Bs[cur ^ 1] + lb0);
      gld16(W + gb1 + kn, Bs[cur ^ 1] + lb1);
    }
    f16x8 af[4], bfr[4];
#pragma unroll
    for (int mi = 0; mi < 4; mi++) {
      int r = wm + mi * 16 + l15;
      int o = r * 32 + ((quad ^ ((r >> 1) & 3)) * 8);
      af[mi] = *(const f16x8*)&As[cur][o];
    }
#pragma unroll
    for (int ni = 0; ni < 4; ni++) {
      int r = wn + ni * 16 + l15;
      int o = r * 32 + ((quad ^ ((r >> 1) & 3)) * 8);
      bfr[ni] = *(const f16x8*)&Bs[cur][o];
    }
#pragma unroll
    for (int mi = 0; mi < 4; mi++)
#pragma unroll
      for (int ni = 0; ni < 4; ni++)
        acc[mi][ni] = __builtin_amdgcn_mfma_f32_16x16x32_f16(
            af[mi], bfr[ni], acc[mi][ni], 0, 0, 0);
    __syncthreads();
    cur ^= 1;
  }
  float bcol[4];
  if constexpr (HAS_BIAS) {
    const int isf = *FLAG;
#pragma unroll
    for (int ni = 0; ni < 4; ni++)
      bcol[ni] = ldi(biasBase, bOff + n0 + wn + ni * 16 + l15, isf);
  }
#pragma unroll
  for (int mi = 0; mi < 4; mi++) {
    int rowg = m0 + wm + mi * 16 + quad * 4;
#pragma unroll
    for (int ni = 0; ni < 4; ni++) {
      int colg = n0 + wn + ni * 16 + l15;
#pragma unroll
      for (int rr = 0; rr < 4; rr++) {
        long off = (long)(rowg + rr) * N + colg;
        float v = acc[mi][ni][rr];
        if constexpr (HAS_BIAS) v += bcol[ni];
        if constexpr (DO_RES) v += R[off];
        if constexpr (DO_GELU) v = gelu_f(v);
        if constexpr (OUT_H) ((_Float16*)Cout)[off] = (_Float16)v;
        else ((float*)Cout)[off] = v;
      }
    }
  }
}

// ---------------------------------------------------------------------------
// top-6 of MV[b,:] + softmax.  grid (32), block 256
// ---------------------------------------------------------------------------
__global__ __launch_bounds__(256) void topk_k(const float* __restrict__ MV,
                                              float* __restrict__ WGT,
                                              int* __restrict__ DLY) {
  int b = blockIdx.x;
  __shared__ float vals[LL];
  __shared__ float rv[256];
  __shared__ int ri[256];
  __shared__ float selv[6];
  int tid = threadIdx.x;
  for (int i = tid; i < LL; i += 256) vals[i] = MV[(long)b * LL + i];
  __syncthreads();
  for (int it = 0; it < 6; it++) {
    float bv = -1e30f;
    int bi = LL - 1;
    for (int i = tid; i < LL; i += 256) {
      float v = vals[i];
      if (v > bv || (v == bv && i < bi)) { bv = v; bi = i; }
    }
    rv[tid] = bv; ri[tid] = bi;
    __syncthreads();
    for (int st = 128; st > 0; st >>= 1) {
      if (tid < st) {
        float ov = rv[tid + st]; int oi = ri[tid + st];
        if (ov > rv[tid] || (ov == rv[tid] && oi < ri[tid])) {
          rv[tid] = ov; ri[tid] = oi;
        }
      }
      __syncthreads();
    }
    if (tid == 0) {
      selv[it] = rv[0];
      DLY[b * 6 + it] = ri[0];
      vals[ri[0]] = -1e30f;
    }
    __syncthreads();
  }
  if (tid == 0) {
    float mx = selv[0];
    float e[6], s = 0.0f;
    for (int i = 0; i < 6; i++) { e[i] = expf(selv[i] - mx); s += e[i]; }
    for (int i = 0; i < 6; i++) WGT[b * 6 + i] = e[i] / s;
  }
}

// ---------------------------------------------------------------------------
// time-delay aggregation, fp16 in/out (chunk-local): grid (1024, NB), block 128
// ---------------------------------------------------------------------------
__global__ __launch_bounds__(128) void agg_k(const _Float16* __restrict__ V,
                                             const float* __restrict__ WGT,
                                             const int* __restrict__ DLY,
                                             _Float16* __restrict__ O) {
  int l = blockIdx.x, b = blockIdx.y;
  int tid = threadIdx.x;
  float w[6]; int dl[6];
#pragma unroll
  for (int i = 0; i < 6; i++) { w[i] = WGT[b * 6 + i]; dl[i] = DLY[b * 6 + i]; }
  long base = (long)b * LL * DD;
  int d = tid * 4;
  float a0 = 0, a1 = 0, a2 = 0, a3 = 0;
#pragma unroll
  for (int i = 0; i < 6; i++) {
    int row = (l + dl[i]) & (LL - 1);
    H4 t; t.u = *(const uint2*)&V[base + (long)row * DD + d];
    a0 += w[i] * (float)t.h[0];
    a1 += w[i] * (float)t.h[1];
    a2 += w[i] * (float)t.h[2];
    a3 += w[i] * (float)t.h[3];
  }
  H4 r;
  r.h[0] = (_Float16)a0; r.h[1] = (_Float16)a1;
  r.h[2] = (_Float16)a2; r.h[3] = (_Float16)a3;
  *(uint2*)&O[base + (long)l * DD + d] = r.u;
}

// ---------------------------------------------------------------------------
// series_decomp residual (f32 out only, race-free). grid (2, 16, 32), block 256
// ---------------------------------------------------------------------------
__global__ __launch_bounds__(256) void decomp_k(const float* __restrict__ Xin,
                                                float* __restrict__ Out) {
  int d = blockIdx.x * 256 + threadIdx.x;
  int l0 = blockIdx.y * 64;
  int b = blockIdx.z;
  const float* xb = Xin + (long)b * LL * DD + d;
  float* ob = Out + (long)b * LL * DD + d;
  float wsum = 0.0f;
  for (int j = l0 - 12; j <= l0 + 12; j++) {
    int jj = min(max(j, 0), LL - 1);
    wsum += xb[(long)jj * DD];
  }
  for (int l = l0; l < l0 + 64; l++) {
    float xv = xb[(long)l * DD];
    ob[(long)l * DD] = xv - wsum * (1.0f / 25.0f);
    int ja = min(l + 13, LL - 1);
    int jr = max(l - 12, 0);
    wsum += xb[(long)ja * DD] - xb[(long)jr * DD];
  }
}

// special layernorm. grid (1024,32), block 256
__global__ __launch_bounds__(256) void ln_k(const float* __restrict__ X,
                                            const void* __restrict__ g,
                                            const void* __restrict__ be,
                                            float* __restrict__ XHo,
                                            const int* __restrict__ FLAG) {
  const int isf = *FLAG;
  int l = blockIdx.x, b = blockIdx.y;
  const float* xr = X + ((long)b * LL + l) * DD;
  int tid = threadIdx.x;
  float x0 = xr[tid], x1 = xr[tid + 256];
  __shared__ float rs[256], rq[256];
  rs[tid] = x0 + x1;
  rq[tid] = x0 * x0 + x1 * x1;
  __syncthreads();
  for (int st = 128; st > 0; st >>= 1) {
    if (tid < st) { rs[tid] += rs[tid + st]; rq[tid] += rq[tid + st]; }
    __syncthreads();
  }
  float mu = rs[0] * (1.0f / 512.0f);
  float var = rq[0] * (1.0f / 512.0f) - mu * mu;
  float rstd = rsqrtf(var + 1e-5f);
  float* o = XHo + ((long)b * LL + l) * DD;
  o[tid] = (x0 - mu) * rstd * ldi(g, tid, isf) + ldi(be, tid, isf);
  o[tid + 256] = (x1 - mu) * rstd * ldi(g, tid + 256, isf) + ldi(be, tid + 256, isf);
}

// column-mean partials. grid (2, 8, 32), block 256: part sums 128 rows.
__global__ __launch_bounds__(256) void colmean_k(const float* __restrict__ XHo,
                                                 float* __restrict__ CMp) {
  int d = blockIdx.x * 256 + threadIdx.x;
  int part = blockIdx.y;
  int b = blockIdx.z;
  const float* p = XHo + (long)b * LL * DD + (long)part * 128 * DD + d;
  float s = 0.0f;
  for (int l = 0; l < 128; l++) s += p[(long)l * DD];
  CMp[((long)part * BB + b) * DD + d] = s;
}

// OUT = gelu(XH - mean) * mark. grid (1024,32), block 256
__global__ __launch_bounds__(256) void geluout_k(const float* __restrict__ XHo,
                                                 const float* __restrict__ CMp,
                                                 const void* __restrict__ mark,
                                                 float* __restrict__ OUT,
                                                 const int* __restrict__ FLAG) {
  const int isf = *FLAG;
  int l = blockIdx.x, b = blockIdx.y;
  int tid = threadIdx.x;
  float mk = ldi(mark, (long)b * LL + l, isf);
  long off = ((long)b * LL + l) * DD;
#pragma unroll
  for (int h = 0; h < 2; h++) {
    int d = tid + h * 256;
    float cs = 0.0f;
#pragma unroll
    for (int p = 0; p < 8; p++) cs += CMp[((long)p * BB + b) * DD + d];
    float v = XHo[off + d] - cs * (1.0f / 1024.0f);
    OUT[off + d] = gelu_f(v) * mk;
  }
}

// ---------------------------------------------------------------------------
// proj stage 1 v2: read-once split-K. grid (512), block 256.
// ---------------------------------------------------------------------------
__global__ __launch_bounds__(256) void proj1_k(const float* __restrict__ OUT,
                                               const void* __restrict__ Wp,
                                               float* __restrict__ PB2,
                                               const int* __restrict__ FLAG) {
  const int isf = *FLAG;
  const int blk = blockIdx.x;
  const int tid = threadIdx.x;
  const int wave = tid >> 6, lane = tid & 63;
  const int grp = lane >> 4, ln = lane & 15;
  const long e = (long)blk * 1024 + tid * 4;
  float w[10][4];
  if (isf) {
    const float* wp = (const float*)Wp;
#pragma unroll
    for (int n = 0; n < 10; n++) {
      float4 t = *(const float4*)&wp[(long)n * 524288 + e];
      w[n][0] = t.x; w[n][1] = t.y; w[n][2] = t.z; w[n][3] = t.w;
    }
  } else {
    const u16* wp = (const u16*)Wp;
#pragma unroll
    for (int n = 0; n < 10; n++) {
      uint2 u = *(const uint2*)&wp[(long)n * 524288 + e];
      w[n][0] = bf2f((u16)(u.x & 0xffff));
      w[n][1] = bf2f((u16)(u.x >> 16));
      w[n][2] = bf2f((u16)(u.y & 0xffff));
      w[n][3] = bf2f((u16)(u.y >> 16));
    }
  }
  __shared__ float sm[4][4][BB][16];  // [wave][grp][b][n] = 32 KB
  float4 xn = *(const float4*)&OUT[e];  // prefetch b=0
  for (int b = 0; b < BB; b++) {
    float4 x = xn;
    if (b < BB - 1) xn = *(const float4*)&OUT[(long)(b + 1) * 524288 + e];
    float acc[10];
#pragma unroll
    for (int n = 0; n < 10; n++)
      acc[n] = x.x * w[n][0] + x.y * w[n][1] + x.z * w[n][2] + x.w * w[n][3];
#pragma unroll
    for (int s = 1; s <= 8; s <<= 1)
#pragma unroll
      for (int n = 0; n < 10; n++) acc[n] += __shfl_xor(acc[n], s, 64);
    float v = 0.0f;
#pragma unroll
    for (int n = 0; n < 10; n++) v = (ln == n) ? acc[n] : v;
    if (ln < 10) sm[wave][grp][b][ln] = v;
  }
  __syncthreads();
  for (int o = tid; o < BB * 10; o += 256) {
    int b = o / 10, n = o - b * 10;
    float s = 0.0f;
#pragma unroll
    for (int w4 = 0; w4 < 4; w4++)
#pragma unroll
      for (int g = 0; g < 4; g++) s += sm[w4][g][b][n];
    PB2[(long)o * 512 + blk] = s;
  }
}

// proj stage 2 v2: reduce 512 partials per (b,n). grid (10,32), block 64
__global__ __launch_bounds__(64) void proj2_k(const float* __restrict__ PB2,
                                              const void* __restrict__ bp,
                                              void* __restrict__ out,
                                              const int* __restrict__ FLAG) {
  const int isf = *FLAG;
  int n = blockIdx.x, b = blockIdx.y;
  int o = b * 10 + n;
  int tid = threadIdx.x;
  float s = 0.0f;
  for (int j = tid; j < 512; j += 64) s += PB2[(long)o * 512 + j];
#pragma unroll
  for (int st = 32; st > 0; st >>= 1) s += __shfl_xor(s, st, 64);
  if (tid == 0) {
    s += ldi(bp, n, isf);
    if (isf) ((float*)out)[o] = s;
    else ((u16*)out)[o] = f2bf(s);
  }
}

// ---------------------------------------------------------------------------
extern "C" void kernel_launch(void* const* d_in, const int* in_sizes, int n_in,
                              void* d_out, int out_size, void* d_ws, size_t ws_size,
                              hipStream_t stream) {
  const void* xe = d_in[0];
  const void* mark = d_in[1];
  const void* cw = d_in[2];
  const void* Wq = d_in[3];
  const void* Wk = d_in[5];
  const void* Wv = d_in[7];
  const void* bv = d_in[8];
  const void* Wo = d_in[9];
  const void* bo = d_in[10];
  const void* Wff1 = d_in[11];
  const void* Wff2 = d_in[12];
  const void* lng = d_in[13];
  const void* lnb = d_in[14];
  const void* Wp = d_in[15];
  const void* bp = d_in[16];

  char* ws = (char*)d_ws;
  float* X      = (float*)(ws + 0L);               // 64 MiB f32 residual
  _Float16* XH  = (_Float16*)(ws + 67108864L);     // fp16 X-high, 32 MiB
  _Float16* XL  = (_Float16*)(ws + 100663296L);    // fp16 X-low*512 / AGh
  _Float16* AGh = (_Float16*)(ws + 100663296L);
  _Float16* ZH  = (_Float16*)(ws + 134217728L);    // Z-high chunk, 4 MiB
  _Float16* ZL  = (_Float16*)(ws + 138412032L);    // Z-low chunk, 4 MiB
  _Float16* Ph  = (_Float16*)(ws + 134217728L);    // Phase B: 8 MiB chunk
  float* CMp    = (float*)(ws + 134217728L);       // final: colmean partials
  float* wT     = (float*)(ws + 142606336L);       // conv wT (dead after embed)
  // Phase A overlays (all dead by Phase B):
  _Float16* KTH = (_Float16*)(ws + 142606336L);    // Wk^T split hi, 0.5 MiB
  _Float16* KTL = (_Float16*)(ws + 143130624L);    // Wk^T split lo
  _Float16* QTH = (_Float16*)(ws + 143654912L);    // Wq^T split hi
  _Float16* QTL = (_Float16*)(ws + 144179200L);    // Wq^T split lo
  _Float16* GH  = (_Float16*)(ws + 144703488L);    // G split hi, 0.5 MiB
  _Float16* GL  = (_Float16*)(ws + 145227776L);    // G split lo
  // Phase B overlays:
  _Float16* Wvh = (_Float16*)(ws + 142606336L);
  _Float16* Woh = (_Float16*)(ws + 143130624L);
  _Float16* W1h = (_Float16*)(ws + 143654912L);    // 2 MiB
  _Float16* W2h = (_Float16*)(ws + 145752064L);    // 2 MiB
  float* MV  = (float*)(ws + 147849216L);
  float* WGT = (float*)(ws + 147980288L);
  int*   DLY = (int*)(ws + 147981312L);
  int*  FLAG = (int*)(ws + 148068352L);
  float* S2  = (float*)(ws + 67108864L);           // FFN f32 (spans XH+XL)
  float* PB2 = (float*)(ws + 67108864L);           // proj partials (S2 dead)
  _Float16* Hb = (_Float16*)X;                     // FFN hidden (X dead)

  const long AD = (long)LL * DD;   // 524288
  const int M = BB * LL;           // 32768

  detect_k<<<1, 64, 0, stream>>>((const uint32_t*)mark, FLAG);
  wT_k<<<126, 256, 0, stream>>>(cw, wT, FLAG);
  conv_embed_k<<<dim3(64, 32), 256, 0, stream>>>(xe, wT, X, XH, XL, FLAG);

  for (int l = 0; l < 3; l++) {
    const long oW = (long)l * DD * DD;
    const long oB = (long)l * DD;
    const long oF = (long)l * DFF * DD;

    // ---- Phase A: delay selection via G-trick + fp16x2 split MFMA ----
    tsplit2_k<<<dim3(8, 8, 2), 256, 0, stream>>>(Wk, Wq, oW,
                                                 KTH, KTL, QTH, QTL, FLAG);
    gemm_z<<<dim3(4, 4), 256, 0, stream>>>(KTH, KTL, QTH, QTL,
                                           GH, GL, 512, 512, 512);
    hipMemsetAsync(MV, 0, (long)BB * LL * sizeof(float), stream);
    for (int cb = 0; cb < 8; cb++) {
      const long co = (long)cb * 4 * AD;
      gemm_z<<<dim3(4, 32), 256, 0, stream>>>(
          XH + co, XL + co, GH, GL, ZH, ZL, 4096, DD, DD);
      qkmv_hl<<<dim3(8, 8, 4), 256, 0, stream>>>(
          ZH, ZL, XH + co, XL + co, MV + (long)cb * 4 * LL);
    }
    topk_k<<<32, 256, 0, stream>>>(MV, WGT, DLY);

    // ---- Phase B: fp16 MFMA for V / agg / Wo / FFN ----
    wcvt6_k<<<1280, 256, 0, stream>>>(Wv, Wo, Wff1, Wff2, oW, oF,
                                      Wvh, Woh, W1h, W2h, FLAG);

    // V (fp16) per 8-batch chunk -> Ph (over ZH/ZL, dead), agg -> AGh
    for (int cb = 0; cb < 4; cb++) {
      const _Float16* xh = XH + (long)cb * 8 * AD;
      gemm_h<1 | 8><<<dim3(4, 64), 256, 0, stream>>>(
          xh, Wvh, bv, oB, nullptr, Ph, 8192, DD, DD, FLAG);
      agg_k<<<dim3(1024, 8), 128, 0, stream>>>(
          Ph, WGT + cb * 48, DLY + cb * 48, AGh + (long)cb * 8 * AD);
    }

    // X = X + AGh @ Wo^T + bo (full M, in-place residual)
    gemm_h<1 | 4><<<dim3(4, 256), 256, 0, stream>>>(
        AGh, Woh, bo, oB, X, X, M, DD, DD, FLAG);

    // x = decomp(X) -> S2 f32 (over XH/XL, both dead)
    decomp_k<<<dim3(2, 16, 32), 256, 0, stream>>>(X, S2);

    // FFN per 8-batch chunk: S2 chunk -> fp16 Ph; hidden -> Hb (X region);
    // S2chunk = S2chunk + (gelu-hidden) @ W2^T
    for (int cb = 0; cb < 4; cb++) {
      float* xd = S2 + (long)cb * 8 * AD;
      acvt_k<<<2048, 256, 0, stream>>>(xd, Ph, 4194304);
      gemm_h<2 | 8><<<dim3(16, 64), 256, 0, stream>>>(
          Ph, W1h, nullptr, 0, nullptr, Hb, 8192, DFF, DD, FLAG);
      gemm_h<4><<<dim3(4, 64), 256, 0, stream>>>(
          Hb, W2h, nullptr, 0, xd, xd, 8192, DD, DFF, FLAG);
    }

    // x = decomp(S2) -> X; then split X -> (XH, XL) for next layer
    decomp_k<<<dim3(2, 16, 32), 256, 0, stream>>>(S2, X);
    if (l < 2) split_k<<<8192, 256, 0, stream>>>(X, XH, XL, 16777216);
  }

  // final special layernorm + gelu + mask + projection
  ln_k<<<dim3(1024, 32), 256, 0, stream>>>(X, lng, lnb, S2, FLAG);
  colmean_k<<<dim3(2, 8, 32), 256, 0, stream>>>(S2, CMp);
  geluout_k<<<dim3(1024, 32), 256, 0, stream>>>(S2, CMp, mark, X, FLAG);
  proj1_k<<<512, 256, 0, stream>>>(X, Wp, PB2, FLAG);
  proj2_k<<<dim3(10, 32), 64, 0, stream>>>(PB2, bp, d_out, FLAG);
}

// Round 8
// 3373.465 us; speedup vs baseline: 1.0210x; 1.0210x over previous
//
#include <hip/hip_runtime.h>
#include <cstdint>

// ---------------------------------------------------------------------------
// Autoformer forward — hybrid precision v13 (R18):
//   * R18: counted-vmcnt pipeline (T4) in gemm_h / gemm_z / qkmv_hl:
//     issue tile k+1, `s_waitcnt vmcnt(N)` (N = loads just issued) + raw
//     s_barrier — tile k+1 stays IN FLIGHT across the barrier instead of
//     being drained by __syncthreads' vmcnt(0). Steady-state step drops
//     ~900 -> ~600 cyc for the 1-block/CU latency-bound GEMMs (FFN2 was
//     46.7us at MfmaUtil 12.6%, occ 9.3%). Trailing raw s_barrier guards
//     LDS buffer reuse (ds_reads retire before each wave's MFMAs issue).
//   * R17: gemm_h at BK=32 double-buffered; FFN1 = acvt + fp16 gemm_h.
//   * R16: 2-phase K-loop (verified −183us).
//   * R15: XCD-aware bijective block swizzle.
//   * R14a/R13/R11: conv reg-cache, proj read-once, tsplit2+gemm_z for G.
// Inputs f32 (runtime-detected from x_mark_enc; bf16 fallback kept).
//
// Workspace map: see v12 header (unchanged).
// ---------------------------------------------------------------------------

using u16 = unsigned short;
typedef _Float16 f16x8 __attribute__((ext_vector_type(8)));
typedef float f32x4 __attribute__((ext_vector_type(4)));

#define BB 32
#define LL 1024
#define DD 512
#define DFF 2048

__device__ __forceinline__ float bf2f(u16 u) {
  union { uint32_t i; float f; } v; v.i = ((uint32_t)u) << 16; return v.f;
}
__device__ __forceinline__ u16 f2bf(float f) {
  union { float f; uint32_t i; } v; v.f = f;
  uint32_t r = (v.i + 0x7FFFu + ((v.i >> 16) & 1u)) >> 16;
  return (u16)r;
}
__device__ __forceinline__ float ldi(const void* p, long i, int isf) {
  return isf ? ((const float*)p)[i] : bf2f(((const u16*)p)[i]);
}
__device__ __forceinline__ float gelu_f(float x) {
  return 0.5f * x * (1.0f + erff(x * 0.70710678118654752440f));
}
// async 16B global -> LDS (wave-uniform LDS base + lane*16)
__device__ __forceinline__ void gld16(const void* g, void* l) {
  __builtin_amdgcn_global_load_lds(
      (const __attribute__((address_space(1))) void*)g,
      (__attribute__((address_space(3))) void*)l, 16, 0, 0);
}
// counted vmcnt wait (immediate) — leaves N newest VMEM ops in flight
template <int N>
__device__ __forceinline__ void vmwait() {
  if constexpr (N == 0) asm volatile("s_waitcnt vmcnt(0)" ::: "memory");
  else if constexpr (N == 4) asm volatile("s_waitcnt vmcnt(4)" ::: "memory");
  else asm volatile("s_waitcnt vmcnt(8)" ::: "memory");
}
// XCD-aware bijective block swizzle (requires nwg % 8 == 0, all grids comply)
__device__ __forceinline__ void swz8(int& bx, int& by) {
  int gx = gridDim.x;
  int nwg = gx * gridDim.y;
  int bid = by * gx + bx;
  int q = nwg >> 3;
  int s = (bid & 7) * q + (bid >> 3);
  bx = s % gx;
  by = s / gx;
}

union H8 { f16x8 v; uint4 u; _Float16 h[8]; };
union H4 { uint2 u; _Float16 h[4]; };

__global__ void detect_k(const uint32_t* __restrict__ mark, int* __restrict__ FLAG) {
  if (threadIdx.x == 0) FLAG[0] = (mark[0] == 0x3F800000u) ? 1 : 0;
}

// transpose conv weight to wT[(c*3+t)*512 + d], f32. grid 126, block 256
__global__ __launch_bounds__(256) void wT_k(const void* __restrict__ w,
                                            float* __restrict__ wT,
                                            const int* __restrict__ FLAG) {
  const int isf = *FLAG;
  int idx = blockIdx.x * 256 + threadIdx.x;
  if (idx >= 63 * DD) return;
  int c3t = idx / DD;
  int d = idx - c3t * DD;
  wT[idx] = ldi(w, (long)d * 63 + c3t, isf);
}

// ---------------------------------------------------------------------------
// Conv1d circular embedding + fused split. grid (L/16, B), block 256.
// ---------------------------------------------------------------------------
__global__ __launch_bounds__(256) void conv_embed_k(
    const void* __restrict__ xe, const float* __restrict__ wT,
    float* __restrict__ X, _Float16* __restrict__ XH, _Float16* __restrict__ XL,
    const int* __restrict__ FLAG) {
  const int isf = *FLAG;
  int b = blockIdx.y;
  int l0 = blockIdx.x * 16;
  __shared__ float xs[18][21];
  int tid = threadIdx.x;
  for (int i = tid; i < 18 * 21; i += 256) {
    int r = i / 21, c = i % 21;
    int row = (l0 - 1 + r + LL) & (LL - 1);
    xs[r][c] = ldi(xe, ((long)b * LL + row) * 21 + c, isf);
  }
  __syncthreads();
  float acc0[16], acc1[16];
#pragma unroll
  for (int ll = 0; ll < 16; ll++) { acc0[ll] = 0.0f; acc1[ll] = 0.0f; }
  for (int c = 0; c < 21; c++) {
    float xreg[18];
#pragma unroll
    for (int r = 0; r < 18; r++) xreg[r] = xs[r][c];
#pragma unroll
    for (int t = 0; t < 3; t++) {
      float w0 = wT[(c * 3 + t) * DD + tid];
      float w1 = wT[(c * 3 + t) * DD + tid + 256];
#pragma unroll
      for (int ll = 0; ll < 16; ll++) {
        acc0[ll] = fmaf(w0, xreg[t + ll], acc0[ll]);
        acc1[ll] = fmaf(w1, xreg[t + ll], acc1[ll]);
      }
    }
  }
#pragma unroll
  for (int ll = 0; ll < 16; ll++) {
    long base = ((long)b * LL + l0 + ll) * DD;
    float v0 = acc0[ll], v1 = acc1[ll];
    X[base + tid] = v0;
    X[base + tid + 256] = v1;
    _Float16 h0 = (_Float16)v0, h1 = (_Float16)v1;
    XH[base + tid] = h0;
    XH[base + tid + 256] = h1;
    XL[base + tid] = (_Float16)((v0 - (float)h0) * 512.0f);
    XL[base + tid + 256] = (_Float16)((v1 - (float)h1) * 512.0f);
  }
}

// ---------------------------------------------------------------------------
// transpose + split BOTH Wq/Wk in one launch. grid (8, 8, 2), block 256.
// ---------------------------------------------------------------------------
__global__ __launch_bounds__(256) void tsplit2_k(
    const void* __restrict__ W1, const void* __restrict__ W2, long off,
    _Float16* __restrict__ T1H, _Float16* __restrict__ T1L,
    _Float16* __restrict__ T2H, _Float16* __restrict__ T2L,
    const int* __restrict__ FLAG) {
  const int isf = *FLAG;
  const void* W = blockIdx.z ? W2 : W1;
  _Float16* TH = blockIdx.z ? T2H : T1H;
  _Float16* TL = blockIdx.z ? T2L : T1L;
  __shared__ float t[64][65];
  const int f0 = blockIdx.x * 64, m0 = blockIdx.y * 64;
  const int tid = threadIdx.x;
  const int c = tid & 63, rb = tid >> 6;
#pragma unroll
  for (int r = rb; r < 64; r += 4)
    t[r][c] = ldi(W, off + (long)(f0 + r) * DD + m0 + c, isf);
  __syncthreads();
#pragma unroll
  for (int r = rb; r < 64; r += 4) {
    float v = t[c][r];
    long o = (long)(m0 + r) * DD + f0 + c;
    _Float16 hv = (_Float16)v;
    TH[o] = hv;
    TL[o] = (_Float16)((v - (float)hv) * 512.0f);
  }
}

// split f32 -> (fp16 high, fp16 low*512). 8 elems/thread.
__global__ __launch_bounds__(256) void split_k(const float* __restrict__ src,
                                               _Float16* __restrict__ dh,
                                               _Float16* __restrict__ dl, int n) {
  long i = ((long)blockIdx.x * 256 + threadIdx.x) * 8;
  if (i >= n) return;
  float4 a = *(const float4*)(src + i);
  float4 b = *(const float4*)(src + i + 4);
  float x[8] = {a.x, a.y, a.z, a.w, b.x, b.y, b.z, b.w};
  H8 h, l;
#pragma unroll
  for (int j = 0; j < 8; j++) {
    _Float16 hv = (_Float16)x[j];
    h.h[j] = hv;
    l.h[j] = (_Float16)((x[j] - (float)hv) * 512.0f);
  }
  *(uint4*)(dh + i) = h.u;
  *(uint4*)(dl + i) = l.u;
}

// convert f32 -> fp16 (plain), 8 elems/thread
__global__ __launch_bounds__(256) void acvt_k(const float* __restrict__ src,
                                              _Float16* __restrict__ dst, int n) {
  long i = ((long)blockIdx.x * 256 + threadIdx.x) * 8;
  if (i >= n) return;
  float4 a = *(const float4*)(src + i);
  float4 b = *(const float4*)(src + i + 4);
  H8 r;
  r.h[0] = (_Float16)a.x; r.h[1] = (_Float16)a.y;
  r.h[2] = (_Float16)a.z; r.h[3] = (_Float16)a.w;
  r.h[4] = (_Float16)b.x; r.h[5] = (_Float16)b.y;
  r.h[6] = (_Float16)b.z; r.h[7] = (_Float16)b.w;
  *(uint4*)(dst + i) = r.u;
}

// all four Phase-B weights -> fp16 in one launch. grid 1280, block 256
__global__ __launch_bounds__(256) void wcvt6_k(
    const void* __restrict__ Wv, const void* __restrict__ Wo,
    const void* __restrict__ W1, const void* __restrict__ W2,
    long oW, long oF,
    _Float16* __restrict__ Wvh, _Float16* __restrict__ Woh,
    _Float16* __restrict__ W1h, _Float16* __restrict__ W2h,
    const int* __restrict__ FLAG) {
  const int isf = *FLAG;
  long e = ((long)blockIdx.x * 256 + threadIdx.x) * 8;
  const void* src; long soff; _Float16* dst;
  if (e < 262144) { src = Wv; soff = oW + e; dst = Wvh + e; }
  else if (e < 524288) { src = Wo; soff = oW + (e - 262144); dst = Woh + (e - 262144); }
  else if (e < 1572864) { src = W1; soff = oF + (e - 524288); dst = W1h + (e - 524288); }
  else { src = W2; soff = oF + (e - 1572864); dst = W2h + (e - 1572864); }
  H8 r;
  if (isf) {
    const float* s = (const float*)src + soff;
    float4 a = *(const float4*)s;
    float4 b = *(const float4*)(s + 4);
    r.h[0] = (_Float16)a.x; r.h[1] = (_Float16)a.y;
    r.h[2] = (_Float16)a.z; r.h[3] = (_Float16)a.w;
    r.h[4] = (_Float16)b.x; r.h[5] = (_Float16)b.y;
    r.h[6] = (_Float16)b.z; r.h[7] = (_Float16)b.w;
  } else {
    const u16* s = (const u16*)src + soff;
    uint4 u = *(const uint4*)s;
    r.h[0] = (_Float16)bf2f((u16)(u.x & 0xffff));
    r.h[1] = (_Float16)bf2f((u16)(u.x >> 16));
    r.h[2] = (_Float16)bf2f((u16)(u.y & 0xffff));
    r.h[3] = (_Float16)bf2f((u16)(u.y >> 16));
    r.h[4] = (_Float16)bf2f((u16)(u.z & 0xffff));
    r.h[5] = (_Float16)bf2f((u16)(u.z >> 16));
    r.h[6] = (_Float16)bf2f((u16)(u.w & 0xffff));
    r.h[7] = (_Float16)bf2f((u16)(u.w >> 16));
  }
  *(uint4*)(dst) = r.u;
}

// ---------------------------------------------------------------------------
// split-fp16 MFMA GEMM: Z = A @ W^T (split in/out). BK=32.
// R18: counted-vmcnt pipeline (8 loads/tile stay in flight across barrier).
// ---------------------------------------------------------------------------
__global__ __launch_bounds__(256) void gemm_z(
    const _Float16* __restrict__ Ah, const _Float16* __restrict__ Al,
    const _Float16* __restrict__ Bh, const _Float16* __restrict__ Bl,
    _Float16* __restrict__ Zh, _Float16* __restrict__ Zl,
    int M, int N, int K) {
  __shared__ __align__(16) _Float16 AsH[2][128 * 32];
  __shared__ __align__(16) _Float16 AsL[2][128 * 32];
  __shared__ __align__(16) _Float16 BsH[2][128 * 32];
  __shared__ __align__(16) _Float16 BsL[2][128 * 32];
  int bx = blockIdx.x, by = blockIdx.y;
  swz8(bx, by);
  const int n0 = bx * 128, m0 = by * 128;
  const int tid = threadIdx.x;
  const int lane = tid & 63, wvi = tid >> 6;
  const int wm = (wvi >> 1) * 64, wn = (wvi & 1) * 64;
  const int l15 = lane & 15, quad = lane >> 4;
  const int ib = wvi * 128 + lane;
  const int r0 = ib >> 2, r1 = r0 + 16;
  const int c0 = ((ib & 3) ^ ((r0 >> 1) & 3)) * 8;
  const int c1 = ((ib & 3) ^ ((r1 >> 1) & 3)) * 8;
  const int lb0 = wvi * 1024, lb1 = wvi * 1024 + 512;
  const long ga0 = (long)(m0 + r0) * K + c0;
  const long ga1 = (long)(m0 + r1) * K + c1;
  const long gb0 = (long)(n0 + r0) * K + c0;
  const long gb1 = (long)(n0 + r1) * K + c1;
  f32x4 aM[4][4], aC[4][4];
#pragma unroll
  for (int i = 0; i < 4; i++)
#pragma unroll
    for (int j = 0; j < 4; j++) {
      aM[i][j] = (f32x4){0.f, 0.f, 0.f, 0.f};
      aC[i][j] = (f32x4){0.f, 0.f, 0.f, 0.f};
    }
  // prologue: issue tile 0 (no drain — iter 0's counted wait handles it)
  gld16(Ah + ga0, AsH[0] + lb0);
  gld16(Ah + ga1, AsH[0] + lb1);
  gld16(Al + ga0, AsL[0] + lb0);
  gld16(Al + ga1, AsL[0] + lb1);
  gld16(Bh + gb0, BsH[0] + lb0);
  gld16(Bh + gb1, BsH[0] + lb1);
  gld16(Bl + gb0, BsL[0] + lb0);
  gld16(Bl + gb1, BsL[0] + lb1);
  int cur = 0;
  for (int k0 = 0; k0 < K; k0 += 32) {
    const int kn = k0 + 32;
    if (kn < K) {  // prefetch next tile, then wait only for CURRENT tile
      gld16(Ah + ga0 + kn, AsH[cur ^ 1] + lb0);
      gld16(Ah + ga1 + kn, AsH[cur ^ 1] + lb1);
      gld16(Al + ga0 + kn, AsL[cur ^ 1] + lb0);
      gld16(Al + ga1 + kn, AsL[cur ^ 1] + lb1);
      gld16(Bh + gb0 + kn, BsH[cur ^ 1] + lb0);
      gld16(Bh + gb1 + kn, BsH[cur ^ 1] + lb1);
      gld16(Bl + gb0 + kn, BsL[cur ^ 1] + lb0);
      gld16(Bl + gb1 + kn, BsL[cur ^ 1] + lb1);
      vmwait<8>();
    } else {
      vmwait<0>();
    }
    __builtin_amdgcn_s_barrier();   // tile k complete in LDS (all waves)
    f16x8 fah[4], fal[4], fbh[4], fbl[4];
#pragma unroll
    for (int mi = 0; mi < 4; mi++) {
      int r = wm + mi * 16 + l15;
      int o = r * 32 + ((quad ^ ((r >> 1) & 3)) * 8);
      fah[mi] = *(const f16x8*)&AsH[cur][o];
      fal[mi] = *(const f16x8*)&AsL[cur][o];
    }
#pragma unroll
    for (int ni = 0; ni < 4; ni++) {
      int r = wn + ni * 16 + l15;
      int o = r * 32 + ((quad ^ ((r >> 1) & 3)) * 8);
      fbh[ni] = *(const f16x8*)&BsH[cur][o];
      fbl[ni] = *(const f16x8*)&BsL[cur][o];
    }
#pragma unroll
    for (int mi = 0; mi < 4; mi++)
#pragma unroll
      for (int ni = 0; ni < 4; ni++) {
        aM[mi][ni] = __builtin_amdgcn_mfma_f32_16x16x32_f16(
            fah[mi], fbh[ni], aM[mi][ni], 0, 0, 0);
        aC[mi][ni] = __builtin_amdgcn_mfma_f32_16x16x32_f16(
            fah[mi], fbl[ni], aC[mi][ni], 0, 0, 0);
        aC[mi][ni] = __builtin_amdgcn_mfma_f32_16x16x32_f16(
            fal[mi], fbh[ni], aC[mi][ni], 0, 0, 0);
      }
    __builtin_amdgcn_s_barrier();   // guard buf[cur] before next-iter overwrite
    cur ^= 1;
  }
#pragma unroll
  for (int mi = 0; mi < 4; mi++) {
    int rowg = m0 + wm + mi * 16 + quad * 4;
#pragma unroll
    for (int ni = 0; ni < 4; ni++) {
      int colg = n0 + wn + ni * 16 + l15;
#pragma unroll
      for (int rr = 0; rr < 4; rr++) {
        long off = (long)(rowg + rr) * N + colg;
        float z = aM[mi][ni][rr] + aC[mi][ni][rr] * (1.0f / 512.0f);
        _Float16 zh = (_Float16)z;
        Zh[off] = zh;
        Zl[off] = (_Float16)((z - (float)zh) * 512.0f);
      }
    }
  }
}

// ---------------------------------------------------------------------------
// split-fp16 MFMA Z.X^T + fused wrapped-diagonal mean reduce. BK=32.
// R18: counted-vmcnt pipeline.
// ---------------------------------------------------------------------------
__global__ __launch_bounds__(256) void qkmv_hl(
    const _Float16* __restrict__ Zh, const _Float16* __restrict__ Zl,
    const _Float16* __restrict__ Xh, const _Float16* __restrict__ Xl,
    float* __restrict__ MV) {
  __shared__ __align__(16) _Float16 AsH[2][128 * 32];
  __shared__ __align__(16) _Float16 AsL[2][128 * 32];
  __shared__ __align__(16) _Float16 BsH[2][128 * 32];
  __shared__ __align__(16) _Float16 BsL[2][128 * 32];
  __shared__ float diag[255];
  const int bz = blockIdx.z;
  const long bb = (long)bz * LL * DD;
  const int n0 = blockIdx.x * 128, m0 = blockIdx.y * 128;
  const int tid = threadIdx.x;
  const int lane = tid & 63, wvi = tid >> 6;
  const int wm = (wvi >> 1) * 64, wn = (wvi & 1) * 64;
  const int l15 = lane & 15, quad = lane >> 4;
  const int ib = wvi * 128 + lane;
  const int r0 = ib >> 2, r1 = r0 + 16;
  const int c0 = ((ib & 3) ^ ((r0 >> 1) & 3)) * 8;
  const int c1 = ((ib & 3) ^ ((r1 >> 1) & 3)) * 8;
  const int lb0 = wvi * 1024, lb1 = wvi * 1024 + 512;
  const long ga0 = bb + (long)(m0 + r0) * DD + c0;
  const long ga1 = bb + (long)(m0 + r1) * DD + c1;
  const long gb0 = bb + (long)(n0 + r0) * DD + c0;
  const long gb1 = bb + (long)(n0 + r1) * DD + c1;
  if (tid < 255) diag[tid] = 0.0f;
  f32x4 aM[4][4], aC[4][4];
#pragma unroll
  for (int i = 0; i < 4; i++)
#pragma unroll
    for (int j = 0; j < 4; j++) {
      aM[i][j] = (f32x4){0.f, 0.f, 0.f, 0.f};
      aC[i][j] = (f32x4){0.f, 0.f, 0.f, 0.f};
    }
  // prologue: issue tile 0
  gld16(Zh + ga0, AsH[0] + lb0);
  gld16(Zh + ga1, AsH[0] + lb1);
  gld16(Zl + ga0, AsL[0] + lb0);
  gld16(Zl + ga1, AsL[0] + lb1);
  gld16(Xh + gb0, BsH[0] + lb0);
  gld16(Xh + gb1, BsH[0] + lb1);
  gld16(Xl + gb0, BsL[0] + lb0);
  gld16(Xl + gb1, BsL[0] + lb1);
  int cur = 0;
  for (int k0 = 0; k0 < DD; k0 += 32) {
    const int kn = k0 + 32;
    if (kn < DD) {
      gld16(Zh + ga0 + kn, AsH[cur ^ 1] + lb0);
      gld16(Zh + ga1 + kn, AsH[cur ^ 1] + lb1);
      gld16(Zl + ga0 + kn, AsL[cur ^ 1] + lb0);
      gld16(Zl + ga1 + kn, AsL[cur ^ 1] + lb1);
      gld16(Xh + gb0 + kn, BsH[cur ^ 1] + lb0);
      gld16(Xh + gb1 + kn, BsH[cur ^ 1] + lb1);
      gld16(Xl + gb0 + kn, BsL[cur ^ 1] + lb0);
      gld16(Xl + gb1 + kn, BsL[cur ^ 1] + lb1);
      vmwait<8>();
    } else {
      vmwait<0>();
    }
    __builtin_amdgcn_s_barrier();
    f16x8 fah[4], fal[4], fbh[4], fbl[4];
#pragma unroll
    for (int mi = 0; mi < 4; mi++) {
      int r = wm + mi * 16 + l15;
      int o = r * 32 + ((quad ^ ((r >> 1) & 3)) * 8);
      fah[mi] = *(const f16x8*)&AsH[cur][o];
      fal[mi] = *(const f16x8*)&AsL[cur][o];
    }
#pragma unroll
    for (int ni = 0; ni < 4; ni++) {
      int r = wn + ni * 16 + l15;
      int o = r * 32 + ((quad ^ ((r >> 1) & 3)) * 8);
      fbh[ni] = *(const f16x8*)&BsH[cur][o];
      fbl[ni] = *(const f16x8*)&BsL[cur][o];
    }
#pragma unroll
    for (int mi = 0; mi < 4; mi++)
#pragma unroll
      for (int ni = 0; ni < 4; ni++) {
        aM[mi][ni] = __builtin_amdgcn_mfma_f32_16x16x32_f16(
            fah[mi], fbh[ni], aM[mi][ni], 0, 0, 0);
        aC[mi][ni] = __builtin_amdgcn_mfma_f32_16x16x32_f16(
            fah[mi], fbl[ni], aC[mi][ni], 0, 0, 0);
        aC[mi][ni] = __builtin_amdgcn_mfma_f32_16x16x32_f16(
            fal[mi], fbh[ni], aC[mi][ni], 0, 0, 0);
      }
    __builtin_amdgcn_s_barrier();
    cur ^= 1;
  }
#pragma unroll
  for (int g = -3; g <= 3; g++) {
#pragma unroll
    for (int rr = 0; rr < 4; rr++) {
      float s = 0.0f;
#pragma unroll
      for (int mi = 0; mi < 4; mi++) {
        int ni = mi - g;
        if (ni >= 0 && ni < 4)
          s += aM[mi][ni][rr] + aC[mi][ni][rr] * (1.0f / 512.0f);
      }
      int d = 127 + (wm - wn) + g * 16 + quad * 4 + rr - l15;
      atomicAdd(&diag[d], s);
    }
  }
  __syncthreads();
  if (tid < 255) {
    int tau = (m0 - n0 + tid - 127 + LL) & (LL - 1);
    atomicAdd(&MV[(long)bz * LL + tau], diag[tid] * (1.0f / 512.0f));
  }
}

// ---------------------------------------------------------------------------
// fp16 MFMA GEMM: C[M,N] = act( A[M,K] @ W[N,K]^T + bias + R )
// R18: BK=32 + counted-vmcnt pipeline (4 loads/tile in flight).
// FLAGS: 1=bias 2=gelu 4=residual 8=out-fp16
// ---------------------------------------------------------------------------
template <int FLAGS>
__global__ __launch_bounds__(256) void gemm_h(
    const _Float16* __restrict__ A, const _Float16* __restrict__ W,
    const void* __restrict__ biasBase, long bOff,
    const float* __restrict__ R, void* __restrict__ Cout,
    int M, int N, int K, const int* __restrict__ FLAG) {
  constexpr bool HAS_BIAS = (FLAGS & 1) != 0;
  constexpr bool DO_GELU = (FLAGS & 2) != 0;
  constexpr bool DO_RES = (FLAGS & 4) != 0;
  constexpr bool OUT_H = (FLAGS & 8) != 0;
  __shared__ __align__(16) _Float16 As[2][128 * 32];
  __shared__ __align__(16) _Float16 Bs[2][128 * 32];
  int bx = blockIdx.x, by = blockIdx.y;
  swz8(bx, by);
  const int n0 = bx * 128, m0 = by * 128;
  const int tid = threadIdx.x;
  const int lane = tid & 63, wvi = tid >> 6;
  const int wm = (wvi >> 1) * 64, wn = (wvi & 1) * 64;
  const int l15 = lane & 15, quad = lane >> 4;
  const int ib = wvi * 128 + lane;
  const int r0 = ib >> 2, r1 = r0 + 16;
  const int c0 = ((ib & 3) ^ ((r0 >> 1) & 3)) * 8;
  const int c1 = ((ib & 3) ^ ((r1 >> 1) & 3)) * 8;
  const int lb0 = wvi * 1024, lb1 = wvi * 1024 + 512;
  const long ga0 = (long)(m0 + r0) * K + c0;
  const long ga1 = (long)(m0 + r1) * K + c1;
  const long gb0 = (long)(n0 + r0) * K + c0;
  const long gb1 = (long)(n0 + r1) * K + c1;
  f32x4 acc[4][4];
#pragma unroll
  for (int i = 0; i < 4; i++)
#pragma unroll
    for (int j = 0; j < 4; j++) acc[i][j] = (f32x4){0.f, 0.f, 0.f, 0.f};
  // prologue: issue tile 0
  gld16(A + ga0, As[0] + lb0);
  gld16(A + ga1, As[0] + lb1);
  gld16(W + gb0, Bs[0] + lb0);
  gld16(W + gb1, Bs[0] + lb1);
  int cur = 0;
  for (int k0 = 0; k0 < K; k0 += 32) {
    const int kn = k0 + 32;
    if (kn < K) {  // prefetch next tile, wait only for current
      gld16(A + ga0 + kn, As[cur ^ 1] + lb0);
      gld16(A + ga1 + kn, As[cur ^ 1] + lb1);
      gld16(W + gb0 + kn, Bs[cur ^ 1] + lb0);
      gld16(W + gb1 + kn, Bs[cur ^ 1] + lb1);
      vmwait<4>();
    } else {
      vmwait<0>();
    }
    __builtin_amdgcn_s_barrier();
    f16x8 af[4], bfr[4];
#pragma unroll
    for (int mi = 0; mi < 4; mi++) {
      int r = wm + mi * 16 + l15;
      int o = r * 32 + ((quad ^ ((r >> 1) & 3)) * 8);
      af[mi] = *(const f16x8*)&As[cur][o];
    }
#pragma unroll
    for (int ni = 0; ni < 4; ni++) {
      int r = wn + ni * 16 + l15;
      int o = r * 32 + ((quad ^ ((r >> 1) & 3)) * 8);
      bfr[ni] = *(const f16x8*)&Bs[cur][o];
    }
#pragma unroll
    for (int mi = 0; mi < 4; mi++)
#pragma unroll
      for (int ni = 0; ni < 4; ni++)
        acc[mi][ni] = __builtin_amdgcn_mfma_f32_16x16x32_f16(
            af[mi], bfr[ni], acc[mi][ni], 0, 0, 0);
    __builtin_amdgcn_s_barrier();
    cur ^= 1;
  }
  float bcol[4];
  if constexpr (HAS_BIAS) {
    const int isf = *FLAG;
#pragma unroll
    for (int ni = 0; ni < 4; ni++)
      bcol[ni] = ldi(biasBase, bOff + n0 + wn + ni * 16 + l15, isf);
  }
#pragma unroll
  for (int mi = 0; mi < 4; mi++) {
    int rowg = m0 + wm + mi * 16 + quad * 4;
#pragma unroll
    for (int ni = 0; ni < 4; ni++) {
      int colg = n0 + wn + ni * 16 + l15;
#pragma unroll
      for (int rr = 0; rr < 4; rr++) {
        long off = (long)(rowg + rr) * N + colg;
        float v = acc[mi][ni][rr];
        if constexpr (HAS_BIAS) v += bcol[ni];
        if constexpr (DO_RES) v += R[off];
        if constexpr (DO_GELU) v = gelu_f(v);
        if constexpr (OUT_H) ((_Float16*)Cout)[off] = (_Float16)v;
        else ((float*)Cout)[off] = v;
      }
    }
  }
}

// ---------------------------------------------------------------------------
// top-6 of MV[b,:] + softmax.  grid (32), block 256
// ---------------------------------------------------------------------------
__global__ __launch_bounds__(256) void topk_k(const float* __restrict__ MV,
                                              float* __restrict__ WGT,
                                              int* __restrict__ DLY) {
  int b = blockIdx.x;
  __shared__ float vals[LL];
  __shared__ float rv[256];
  __shared__ int ri[256];
  __shared__ float selv[6];
  int tid = threadIdx.x;
  for (int i = tid; i < LL; i += 256) vals[i] = MV[(long)b * LL + i];
  __syncthreads();
  for (int it = 0; it < 6; it++) {
    float bv = -1e30f;
    int bi = LL - 1;
    for (int i = tid; i < LL; i += 256) {
      float v = vals[i];
      if (v > bv || (v == bv && i < bi)) { bv = v; bi = i; }
    }
    rv[tid] = bv; ri[tid] = bi;
    __syncthreads();
    for (int st = 128; st > 0; st >>= 1) {
      if (tid < st) {
        float ov = rv[tid + st]; int oi = ri[tid + st];
        if (ov > rv[tid] || (ov == rv[tid] && oi < ri[tid])) {
          rv[tid] = ov; ri[tid] = oi;
        }
      }
      __syncthreads();
    }
    if (tid == 0) {
      selv[it] = rv[0];
      DLY[b * 6 + it] = ri[0];
      vals[ri[0]] = -1e30f;
    }
    __syncthreads();
  }
  if (tid == 0) {
    float mx = selv[0];
    float e[6], s = 0.0f;
    for (int i = 0; i < 6; i++) { e[i] = expf(selv[i] - mx); s += e[i]; }
    for (int i = 0; i < 6; i++) WGT[b * 6 + i] = e[i] / s;
  }
}

// ---------------------------------------------------------------------------
// time-delay aggregation, fp16 in/out (chunk-local): grid (1024, NB), block 128
// ---------------------------------------------------------------------------
__global__ __launch_bounds__(128) void agg_k(const _Float16* __restrict__ V,
                                             const float* __restrict__ WGT,
                                             const int* __restrict__ DLY,
                                             _Float16* __restrict__ O) {
  int l = blockIdx.x, b = blockIdx.y;
  int tid = threadIdx.x;
  float w[6]; int dl[6];
#pragma unroll
  for (int i = 0; i < 6; i++) { w[i] = WGT[b * 6 + i]; dl[i] = DLY[b * 6 + i]; }
  long base = (long)b * LL * DD;
  int d = tid * 4;
  float a0 = 0, a1 = 0, a2 = 0, a3 = 0;
#pragma unroll
  for (int i = 0; i < 6; i++) {
    int row = (l + dl[i]) & (LL - 1);
    H4 t; t.u = *(const uint2*)&V[base + (long)row * DD + d];
    a0 += w[i] * (float)t.h[0];
    a1 += w[i] * (float)t.h[1];
    a2 += w[i] * (float)t.h[2];
    a3 += w[i] * (float)t.h[3];
  }
  H4 r;
  r.h[0] = (_Float16)a0; r.h[1] = (_Float16)a1;
  r.h[2] = (_Float16)a2; r.h[3] = (_Float16)a3;
  *(uint2*)&O[base + (long)l * DD + d] = r.u;
}

// ---------------------------------------------------------------------------
// series_decomp residual (f32 out only, race-free). grid (2, 16, 32), block 256
// ---------------------------------------------------------------------------
__global__ __launch_bounds__(256) void decomp_k(const float* __restrict__ Xin,
                                                float* __restrict__ Out) {
  int d = blockIdx.x * 256 + threadIdx.x;
  int l0 = blockIdx.y * 64;
  int b = blockIdx.z;
  const float* xb = Xin + (long)b * LL * DD + d;
  float* ob = Out + (long)b * LL * DD + d;
  float wsum = 0.0f;
  for (int j = l0 - 12; j <= l0 + 12; j++) {
    int jj = min(max(j, 0), LL - 1);
    wsum += xb[(long)jj * DD];
  }
  for (int l = l0; l < l0 + 64; l++) {
    float xv = xb[(long)l * DD];
    ob[(long)l * DD] = xv - wsum * (1.0f / 25.0f);
    int ja = min(l + 13, LL - 1);
    int jr = max(l - 12, 0);
    wsum += xb[(long)ja * DD] - xb[(long)jr * DD];
  }
}

// special layernorm. grid (1024,32), block 256
__global__ __launch_bounds__(256) void ln_k(const float* __restrict__ X,
                                            const void* __restrict__ g,
                                            const void* __restrict__ be,
                                            float* __restrict__ XHo,
                                            const int* __restrict__ FLAG) {
  const int isf = *FLAG;
  int l = blockIdx.x, b = blockIdx.y;
  const float* xr = X + ((long)b * LL + l) * DD;
  int tid = threadIdx.x;
  float x0 = xr[tid], x1 = xr[tid + 256];
  __shared__ float rs[256], rq[256];
  rs[tid] = x0 + x1;
  rq[tid] = x0 * x0 + x1 * x1;
  __syncthreads();
  for (int st = 128; st > 0; st >>= 1) {
    if (tid < st) { rs[tid] += rs[tid + st]; rq[tid] += rq[tid + st]; }
    __syncthreads();
  }
  float mu = rs[0] * (1.0f / 512.0f);
  float var = rq[0] * (1.0f / 512.0f) - mu * mu;
  float rstd = rsqrtf(var + 1e-5f);
  float* o = XHo + ((long)b * LL + l) * DD;
  o[tid] = (x0 - mu) * rstd * ldi(g, tid, isf) + ldi(be, tid, isf);
  o[tid + 256] = (x1 - mu) * rstd * ldi(g, tid + 256, isf) + ldi(be, tid + 256, isf);
}

// column-mean partials. grid (2, 8, 32), block 256: part sums 128 rows.
__global__ __launch_bounds__(256) void colmean_k(const float* __restrict__ XHo,
                                                 float* __restrict__ CMp) {
  int d = blockIdx.x * 256 + threadIdx.x;
  int part = blockIdx.y;
  int b = blockIdx.z;
  const float* p = XHo + (long)b * LL * DD + (long)part * 128 * DD + d;
  float s = 0.0f;
  for (int l = 0; l < 128; l++) s += p[(long)l * DD];
  CMp[((long)part * BB + b) * DD + d] = s;
}

// OUT = gelu(XH - mean) * mark. grid (1024,32), block 256
__global__ __launch_bounds__(256) void geluout_k(const float* __restrict__ XHo,
                                                 const float* __restrict__ CMp,
                                                 const void* __restrict__ mark,
                                                 float* __restrict__ OUT,
                                                 const int* __restrict__ FLAG) {
  const int isf = *FLAG;
  int l = blockIdx.x, b = blockIdx.y;
  int tid = threadIdx.x;
  float mk = ldi(mark, (long)b * LL + l, isf);
  long off = ((long)b * LL + l) * DD;
#pragma unroll
  for (int h = 0; h < 2; h++) {
    int d = tid + h * 256;
    float cs = 0.0f;
#pragma unroll
    for (int p = 0; p < 8; p++) cs += CMp[((long)p * BB + b) * DD + d];
    float v = XHo[off + d] - cs * (1.0f / 1024.0f);
    OUT[off + d] = gelu_f(v) * mk;
  }
}

// ---------------------------------------------------------------------------
// proj stage 1 v2: read-once split-K. grid (512), block 256.
// ---------------------------------------------------------------------------
__global__ __launch_bounds__(256) void proj1_k(const float* __restrict__ OUT,
                                               const void* __restrict__ Wp,
                                               float* __restrict__ PB2,
                                               const int* __restrict__ FLAG) {
  const int isf = *FLAG;
  const int blk = blockIdx.x;
  const int tid = threadIdx.x;
  const int wave = tid >> 6, lane = tid & 63;
  const int grp = lane >> 4, ln = lane & 15;
  const long e = (long)blk * 1024 + tid * 4;
  float w[10][4];
  if (isf) {
    const float* wp = (const float*)Wp;
#pragma unroll
    for (int n = 0; n < 10; n++) {
      float4 t = *(const float4*)&wp[(long)n * 524288 + e];
      w[n][0] = t.x; w[n][1] = t.y; w[n][2] = t.z; w[n][3] = t.w;
    }
  } else {
    const u16* wp = (const u16*)Wp;
#pragma unroll
    for (int n = 0; n < 10; n++) {
      uint2 u = *(const uint2*)&wp[(long)n * 524288 + e];
      w[n][0] = bf2f((u16)(u.x & 0xffff));
      w[n][1] = bf2f((u16)(u.x >> 16));
      w[n][2] = bf2f((u16)(u.y & 0xffff));
      w[n][3] = bf2f((u16)(u.y >> 16));
    }
  }
  __shared__ float sm[4][4][BB][16];  // [wave][grp][b][n] = 32 KB
  float4 xn = *(const float4*)&OUT[e];  // prefetch b=0
  for (int b = 0; b < BB; b++) {
    float4 x = xn;
    if (b < BB - 1) xn = *(const float4*)&OUT[(long)(b + 1) * 524288 + e];
    float acc[10];
#pragma unroll
    for (int n = 0; n < 10; n++)
      acc[n] = x.x * w[n][0] + x.y * w[n][1] + x.z * w[n][2] + x.w * w[n][3];
#pragma unroll
    for (int s = 1; s <= 8; s <<= 1)
#pragma unroll
      for (int n = 0; n < 10; n++) acc[n] += __shfl_xor(acc[n], s, 64);
    float v = 0.0f;
#pragma unroll
    for (int n = 0; n < 10; n++) v = (ln == n) ? acc[n] : v;
    if (ln < 10) sm[wave][grp][b][ln] = v;
  }
  __syncthreads();
  for (int o = tid; o < BB * 10; o += 256) {
    int b = o / 10, n = o - b * 10;
    float s = 0.0f;
#pragma unroll
    for (int w4 = 0; w4 < 4; w4++)
#pragma unroll
      for (int g = 0; g < 4; g++) s += sm[w4][g][b][n];
    PB2[(long)o * 512 + blk] = s;
  }
}

// proj stage 2 v2: reduce 512 partials per (b,n). grid (10,32), block 64
__global__ __launch_bounds__(64) void proj2_k(const float* __restrict__ PB2,
                                              const void* __restrict__ bp,
                                              void* __restrict__ out,
                                              const int* __restrict__ FLAG) {
  const int isf = *FLAG;
  int n = blockIdx.x, b = blockIdx.y;
  int o = b * 10 + n;
  int tid = threadIdx.x;
  float s = 0.0f;
  for (int j = tid; j < 512; j += 64) s += PB2[(long)o * 512 + j];
#pragma unroll
  for (int st = 32; st > 0; st >>= 1) s += __shfl_xor(s, st, 64);
  if (tid == 0) {
    s += ldi(bp, n, isf);
    if (isf) ((float*)out)[o] = s;
    else ((u16*)out)[o] = f2bf(s);
  }
}

// ---------------------------------------------------------------------------
extern "C" void kernel_launch(void* const* d_in, const int* in_sizes, int n_in,
                              void* d_out, int out_size, void* d_ws, size_t ws_size,
                              hipStream_t stream) {
  const void* xe = d_in[0];
  const void* mark = d_in[1];
  const void* cw = d_in[2];
  const void* Wq = d_in[3];
  const void* Wk = d_in[5];
  const void* Wv = d_in[7];
  const void* bv = d_in[8];
  const void* Wo = d_in[9];
  const void* bo = d_in[10];
  const void* Wff1 = d_in[11];
  const void* Wff2 = d_in[12];
  const void* lng = d_in[13];
  const void* lnb = d_in[14];
  const void* Wp = d_in[15];
  const void* bp = d_in[16];

  char* ws = (char*)d_ws;
  float* X      = (float*)(ws + 0L);               // 64 MiB f32 residual
  _Float16* XH  = (_Float16*)(ws + 67108864L);     // fp16 X-high, 32 MiB
  _Float16* XL  = (_Float16*)(ws + 100663296L);    // fp16 X-low*512 / AGh
  _Float16* AGh = (_Float16*)(ws + 100663296L);
  _Float16* ZH  = (_Float16*)(ws + 134217728L);    // Z-high chunk, 4 MiB
  _Float16* ZL  = (_Float16*)(ws + 138412032L);    // Z-low chunk, 4 MiB
  _Float16* Ph  = (_Float16*)(ws + 134217728L);    // Phase B: 8 MiB chunk
  float* CMp    = (float*)(ws + 134217728L);       // final: colmean partials
  float* wT     = (float*)(ws + 142606336L);       // conv wT (dead after embed)
  // Phase A overlays (all dead by Phase B):
  _Float16* KTH = (_Float16*)(ws + 142606336L);    // Wk^T split hi, 0.5 MiB
  _Float16* KTL = (_Float16*)(ws + 143130624L);    // Wk^T split lo
  _Float16* QTH = (_Float16*)(ws + 143654912L);    // Wq^T split hi
  _Float16* QTL = (_Float16*)(ws + 144179200L);    // Wq^T split lo
  _Float16* GH  = (_Float16*)(ws + 144703488L);    // G split hi, 0.5 MiB
  _Float16* GL  = (_Float16*)(ws + 145227776L);    // G split lo
  // Phase B overlays:
  _Float16* Wvh = (_Float16*)(ws + 142606336L);
  _Float16* Woh = (_Float16*)(ws + 143130624L);
  _Float16* W1h = (_Float16*)(ws + 143654912L);    // 2 MiB
  _Float16* W2h = (_Float16*)(ws + 145752064L);    // 2 MiB
  float* MV  = (float*)(ws + 147849216L);
  float* WGT = (float*)(ws + 147980288L);
  int*   DLY = (int*)(ws + 147981312L);
  int*  FLAG = (int*)(ws + 148068352L);
  float* S2  = (float*)(ws + 67108864L);           // FFN f32 (spans XH+XL)
  float* PB2 = (float*)(ws + 67108864L);           // proj partials (S2 dead)
  _Float16* Hb = (_Float16*)X;                     // FFN hidden (X dead)

  const long AD = (long)LL * DD;   // 524288
  const int M = BB * LL;           // 32768

  detect_k<<<1, 64, 0, stream>>>((const uint32_t*)mark, FLAG);
  wT_k<<<126, 256, 0, stream>>>(cw, wT, FLAG);
  conv_embed_k<<<dim3(64, 32), 256, 0, stream>>>(xe, wT, X, XH, XL, FLAG);

  for (int l = 0; l < 3; l++) {
    const long oW = (long)l * DD * DD;
    const long oB = (long)l * DD;
    const long oF = (long)l * DFF * DD;

    // ---- Phase A: delay selection via G-trick + fp16x2 split MFMA ----
    tsplit2_k<<<dim3(8, 8, 2), 256, 0, stream>>>(Wk, Wq, oW,
                                                 KTH, KTL, QTH, QTL, FLAG);
    gemm_z<<<dim3(4, 4), 256, 0, stream>>>(KTH, KTL, QTH, QTL,
                                           GH, GL, 512, 512, 512);
    hipMemsetAsync(MV, 0, (long)BB * LL * sizeof(float), stream);
    for (int cb = 0; cb < 8; cb++) {
      const long co = (long)cb * 4 * AD;
      gemm_z<<<dim3(4, 32), 256, 0, stream>>>(
          XH + co, XL + co, GH, GL, ZH, ZL, 4096, DD, DD);
      qkmv_hl<<<dim3(8, 8, 4), 256, 0, stream>>>(
          ZH, ZL, XH + co, XL + co, MV + (long)cb * 4 * LL);
    }
    topk_k<<<32, 256, 0, stream>>>(MV, WGT, DLY);

    // ---- Phase B: fp16 MFMA for V / agg / Wo / FFN ----
    wcvt6_k<<<1280, 256, 0, stream>>>(Wv, Wo, Wff1, Wff2, oW, oF,
                                      Wvh, Woh, W1h, W2h, FLAG);

    // V (fp16) per 8-batch chunk -> Ph (over ZH/ZL, dead), agg -> AGh
    for (int cb = 0; cb < 4; cb++) {
      const _Float16* xh = XH + (long)cb * 8 * AD;
      gemm_h<1 | 8><<<dim3(4, 64), 256, 0, stream>>>(
          xh, Wvh, bv, oB, nullptr, Ph, 8192, DD, DD, FLAG);
      agg_k<<<dim3(1024, 8), 128, 0, stream>>>(
          Ph, WGT + cb * 48, DLY + cb * 48, AGh + (long)cb * 8 * AD);
    }

    // X = X + AGh @ Wo^T + bo (full M, in-place residual)
    gemm_h<1 | 4><<<dim3(4, 256), 256, 0, stream>>>(
        AGh, Woh, bo, oB, X, X, M, DD, DD, FLAG);

    // x = decomp(X) -> S2 f32 (over XH/XL, both dead)
    decomp_k<<<dim3(2, 16, 32), 256, 0, stream>>>(X, S2);

    // FFN per 8-batch chunk: S2 chunk -> fp16 Ph; hidden -> Hb (X region);
    // S2chunk = S2chunk + (gelu-hidden) @ W2^T
    for (int cb = 0; cb < 4; cb++) {
      float* xd = S2 + (long)cb * 8 * AD;
      acvt_k<<<2048, 256, 0, stream>>>(xd, Ph, 4194304);
      gemm_h<2 | 8><<<dim3(16, 64), 256, 0, stream>>>(
          Ph, W1h, nullptr, 0, nullptr, Hb, 8192, DFF, DD, FLAG);
      gemm_h<4><<<dim3(4, 64), 256, 0, stream>>>(
          Hb, W2h, nullptr, 0, xd, xd, 8192, DD, DFF, FLAG);
    }

    // x = decomp(S2) -> X; then split X -> (XH, XL) for next layer
    decomp_k<<<dim3(2, 16, 32), 256, 0, stream>>>(S2, X);
    if (l < 2) split_k<<<8192, 256, 0, stream>>>(X, XH, XL, 16777216);
  }

  // final special layernorm + gelu + mask + projection
  ln_k<<<dim3(1024, 32), 256, 0, stream>>>(X, lng, lnb, S2, FLAG);
  colmean_k<<<dim3(2, 8, 32), 256, 0, stream>>>(S2, CMp);
  geluout_k<<<dim3(1024, 32), 256, 0, stream>>>(S2, CMp, mark, X, FLAG);
  proj1_k<<<512, 256, 0, stream>>>(X, Wp, PB2, FLAG);
  proj2_k<<<dim3(10, 32), 64, 0, stream>>>(PB2, bp, d_out, FLAG);
}

// Round 10
// 3290.259 us; speedup vs baseline: 1.0468x; 1.0253x over previous
//
#include <hip/hip_runtime.h>
#include <cstdint>

// ---------------------------------------------------------------------------
// Autoformer forward — hybrid precision v14 (R19, resubmitted after infra
// failure — source unchanged, re-audited):
//   * R19: gemm_h tile 128x64 (was 128x128): waves 2x2 of 64x32, acc[4][2],
//     LDS 24KB, 3 loads/tile + vmcnt(3). Grid doubles for every caller —
//     FFN2 was 1 block/CU (grid 256) with ZERO TLP; R18's counted-vmcnt
//     could not cover HBM latency alone (45us at 1690 cyc/step vs 650
//     pipeline bound). VGPR/LDS allowed 5 blocks/CU; grid was the limiter.
//     A-staging identical to verified kernel; B = same pattern, half height.
//   * R18: counted-vmcnt pipeline in gemm_z / qkmv_hl / gemm_h (kept).
//   * R17: FFN1 = acvt + fp16 gemm_h.  * R16: 2-phase K-loop (−183us).
//   * R15: XCD swizzle.  * R14a/R13/R11: conv reg-cache, proj v2, tsplit2.
// Inputs f32 (runtime-detected from x_mark_enc; bf16 fallback kept).
// Workspace map: see v12 header (unchanged).
// ---------------------------------------------------------------------------

using u16 = unsigned short;
typedef _Float16 f16x8 __attribute__((ext_vector_type(8)));
typedef float f32x4 __attribute__((ext_vector_type(4)));

#define BB 32
#define LL 1024
#define DD 512
#define DFF 2048

__device__ __forceinline__ float bf2f(u16 u) {
  union { uint32_t i; float f; } v; v.i = ((uint32_t)u) << 16; return v.f;
}
__device__ __forceinline__ u16 f2bf(float f) {
  union { float f; uint32_t i; } v; v.f = f;
  uint32_t r = (v.i + 0x7FFFu + ((v.i >> 16) & 1u)) >> 16;
  return (u16)r;
}
__device__ __forceinline__ float ldi(const void* p, long i, int isf) {
  return isf ? ((const float*)p)[i] : bf2f(((const u16*)p)[i]);
}
__device__ __forceinline__ float gelu_f(float x) {
  return 0.5f * x * (1.0f + erff(x * 0.70710678118654752440f));
}
// async 16B global -> LDS (wave-uniform LDS base + lane*16)
__device__ __forceinline__ void gld16(const void* g, void* l) {
  __builtin_amdgcn_global_load_lds(
      (const __attribute__((address_space(1))) void*)g,
      (__attribute__((address_space(3))) void*)l, 16, 0, 0);
}
// counted vmcnt wait (immediate) — leaves N newest VMEM ops in flight
template <int N>
__device__ __forceinline__ void vmwait() {
  if constexpr (N == 0) asm volatile("s_waitcnt vmcnt(0)" ::: "memory");
  else if constexpr (N == 3) asm volatile("s_waitcnt vmcnt(3)" ::: "memory");
  else if constexpr (N == 4) asm volatile("s_waitcnt vmcnt(4)" ::: "memory");
  else asm volatile("s_waitcnt vmcnt(8)" ::: "memory");
}
// XCD-aware bijective block swizzle (requires nwg % 8 == 0, all grids comply)
__device__ __forceinline__ void swz8(int& bx, int& by) {
  int gx = gridDim.x;
  int nwg = gx * gridDim.y;
  int bid = by * gx + bx;
  int q = nwg >> 3;
  int s = (bid & 7) * q + (bid >> 3);
  bx = s % gx;
  by = s / gx;
}

union H8 { f16x8 v; uint4 u; _Float16 h[8]; };
union H4 { uint2 u; _Float16 h[4]; };

__global__ void detect_k(const uint32_t* __restrict__ mark, int* __restrict__ FLAG) {
  if (threadIdx.x == 0) FLAG[0] = (mark[0] == 0x3F800000u) ? 1 : 0;
}

// transpose conv weight to wT[(c*3+t)*512 + d], f32. grid 126, block 256
__global__ __launch_bounds__(256) void wT_k(const void* __restrict__ w,
                                            float* __restrict__ wT,
                                            const int* __restrict__ FLAG) {
  const int isf = *FLAG;
  int idx = blockIdx.x * 256 + threadIdx.x;
  if (idx >= 63 * DD) return;
  int c3t = idx / DD;
  int d = idx - c3t * DD;
  wT[idx] = ldi(w, (long)d * 63 + c3t, isf);
}

// ---------------------------------------------------------------------------
// Conv1d circular embedding + fused split. grid (L/16, B), block 256.
// ---------------------------------------------------------------------------
__global__ __launch_bounds__(256) void conv_embed_k(
    const void* __restrict__ xe, const float* __restrict__ wT,
    float* __restrict__ X, _Float16* __restrict__ XH, _Float16* __restrict__ XL,
    const int* __restrict__ FLAG) {
  const int isf = *FLAG;
  int b = blockIdx.y;
  int l0 = blockIdx.x * 16;
  __shared__ float xs[18][21];
  int tid = threadIdx.x;
  for (int i = tid; i < 18 * 21; i += 256) {
    int r = i / 21, c = i % 21;
    int row = (l0 - 1 + r + LL) & (LL - 1);
    xs[r][c] = ldi(xe, ((long)b * LL + row) * 21 + c, isf);
  }
  __syncthreads();
  float acc0[16], acc1[16];
#pragma unroll
  for (int ll = 0; ll < 16; ll++) { acc0[ll] = 0.0f; acc1[ll] = 0.0f; }
  for (int c = 0; c < 21; c++) {
    float xreg[18];
#pragma unroll
    for (int r = 0; r < 18; r++) xreg[r] = xs[r][c];
#pragma unroll
    for (int t = 0; t < 3; t++) {
      float w0 = wT[(c * 3 + t) * DD + tid];
      float w1 = wT[(c * 3 + t) * DD + tid + 256];
#pragma unroll
      for (int ll = 0; ll < 16; ll++) {
        acc0[ll] = fmaf(w0, xreg[t + ll], acc0[ll]);
        acc1[ll] = fmaf(w1, xreg[t + ll], acc1[ll]);
      }
    }
  }
#pragma unroll
  for (int ll = 0; ll < 16; ll++) {
    long base = ((long)b * LL + l0 + ll) * DD;
    float v0 = acc0[ll], v1 = acc1[ll];
    X[base + tid] = v0;
    X[base + tid + 256] = v1;
    _Float16 h0 = (_Float16)v0, h1 = (_Float16)v1;
    XH[base + tid] = h0;
    XH[base + tid + 256] = h1;
    XL[base + tid] = (_Float16)((v0 - (float)h0) * 512.0f);
    XL[base + tid + 256] = (_Float16)((v1 - (float)h1) * 512.0f);
  }
}

// ---------------------------------------------------------------------------
// transpose + split BOTH Wq/Wk in one launch. grid (8, 8, 2), block 256.
// ---------------------------------------------------------------------------
__global__ __launch_bounds__(256) void tsplit2_k(
    const void* __restrict__ W1, const void* __restrict__ W2, long off,
    _Float16* __restrict__ T1H, _Float16* __restrict__ T1L,
    _Float16* __restrict__ T2H, _Float16* __restrict__ T2L,
    const int* __restrict__ FLAG) {
  const int isf = *FLAG;
  const void* W = blockIdx.z ? W2 : W1;
  _Float16* TH = blockIdx.z ? T2H : T1H;
  _Float16* TL = blockIdx.z ? T2L : T1L;
  __shared__ float t[64][65];
  const int f0 = blockIdx.x * 64, m0 = blockIdx.y * 64;
  const int tid = threadIdx.x;
  const int c = tid & 63, rb = tid >> 6;
#pragma unroll
  for (int r = rb; r < 64; r += 4)
    t[r][c] = ldi(W, off + (long)(f0 + r) * DD + m0 + c, isf);
  __syncthreads();
#pragma unroll
  for (int r = rb; r < 64; r += 4) {
    float v = t[c][r];
    long o = (long)(m0 + r) * DD + f0 + c;
    _Float16 hv = (_Float16)v;
    TH[o] = hv;
    TL[o] = (_Float16)((v - (float)hv) * 512.0f);
  }
}

// split f32 -> (fp16 high, fp16 low*512). 8 elems/thread.
__global__ __launch_bounds__(256) void split_k(const float* __restrict__ src,
                                               _Float16* __restrict__ dh,
                                               _Float16* __restrict__ dl, int n) {
  long i = ((long)blockIdx.x * 256 + threadIdx.x) * 8;
  if (i >= n) return;
  float4 a = *(const float4*)(src + i);
  float4 b = *(const float4*)(src + i + 4);
  float x[8] = {a.x, a.y, a.z, a.w, b.x, b.y, b.z, b.w};
  H8 h, l;
#pragma unroll
  for (int j = 0; j < 8; j++) {
    _Float16 hv = (_Float16)x[j];
    h.h[j] = hv;
    l.h[j] = (_Float16)((x[j] - (float)hv) * 512.0f);
  }
  *(uint4*)(dh + i) = h.u;
  *(uint4*)(dl + i) = l.u;
}

// convert f32 -> fp16 (plain), 8 elems/thread
__global__ __launch_bounds__(256) void acvt_k(const float* __restrict__ src,
                                              _Float16* __restrict__ dst, int n) {
  long i = ((long)blockIdx.x * 256 + threadIdx.x) * 8;
  if (i >= n) return;
  float4 a = *(const float4*)(src + i);
  float4 b = *(const float4*)(src + i + 4);
  H8 r;
  r.h[0] = (_Float16)a.x; r.h[1] = (_Float16)a.y;
  r.h[2] = (_Float16)a.z; r.h[3] = (_Float16)a.w;
  r.h[4] = (_Float16)b.x; r.h[5] = (_Float16)b.y;
  r.h[6] = (_Float16)b.z; r.h[7] = (_Float16)b.w;
  *(uint4*)(dst + i) = r.u;
}

// all four Phase-B weights -> fp16 in one launch. grid 1280, block 256
__global__ __launch_bounds__(256) void wcvt6_k(
    const void* __restrict__ Wv, const void* __restrict__ Wo,
    const void* __restrict__ W1, const void* __restrict__ W2,
    long oW, long oF,
    _Float16* __restrict__ Wvh, _Float16* __restrict__ Woh,
    _Float16* __restrict__ W1h, _Float16* __restrict__ W2h,
    const int* __restrict__ FLAG) {
  const int isf = *FLAG;
  long e = ((long)blockIdx.x * 256 + threadIdx.x) * 8;
  const void* src; long soff; _Float16* dst;
  if (e < 262144) { src = Wv; soff = oW + e; dst = Wvh + e; }
  else if (e < 524288) { src = Wo; soff = oW + (e - 262144); dst = Woh + (e - 262144); }
  else if (e < 1572864) { src = W1; soff = oF + (e - 524288); dst = W1h + (e - 524288); }
  else { src = W2; soff = oF + (e - 1572864); dst = W2h + (e - 1572864); }
  H8 r;
  if (isf) {
    const float* s = (const float*)src + soff;
    float4 a = *(const float4*)s;
    float4 b = *(const float4*)(s + 4);
    r.h[0] = (_Float16)a.x; r.h[1] = (_Float16)a.y;
    r.h[2] = (_Float16)a.z; r.h[3] = (_Float16)a.w;
    r.h[4] = (_Float16)b.x; r.h[5] = (_Float16)b.y;
    r.h[6] = (_Float16)b.z; r.h[7] = (_Float16)b.w;
  } else {
    const u16* s = (const u16*)src + soff;
    uint4 u = *(const uint4*)s;
    r.h[0] = (_Float16)bf2f((u16)(u.x & 0xffff));
    r.h[1] = (_Float16)bf2f((u16)(u.x >> 16));
    r.h[2] = (_Float16)bf2f((u16)(u.y & 0xffff));
    r.h[3] = (_Float16)bf2f((u16)(u.y >> 16));
    r.h[4] = (_Float16)bf2f((u16)(u.z & 0xffff));
    r.h[5] = (_Float16)bf2f((u16)(u.z >> 16));
    r.h[6] = (_Float16)bf2f((u16)(u.w & 0xffff));
    r.h[7] = (_Float16)bf2f((u16)(u.w >> 16));
  }
  *(uint4*)(dst) = r.u;
}

// ---------------------------------------------------------------------------
// split-fp16 MFMA GEMM: Z = A @ W^T (split in/out). BK=32.
// R18: counted-vmcnt pipeline (8 loads/tile stay in flight across barrier).
// ---------------------------------------------------------------------------
__global__ __launch_bounds__(256) void gemm_z(
    const _Float16* __restrict__ Ah, const _Float16* __restrict__ Al,
    const _Float16* __restrict__ Bh, const _Float16* __restrict__ Bl,
    _Float16* __restrict__ Zh, _Float16* __restrict__ Zl,
    int M, int N, int K) {
  __shared__ __align__(16) _Float16 AsH[2][128 * 32];
  __shared__ __align__(16) _Float16 AsL[2][128 * 32];
  __shared__ __align__(16) _Float16 BsH[2][128 * 32];
  __shared__ __align__(16) _Float16 BsL[2][128 * 32];
  int bx = blockIdx.x, by = blockIdx.y;
  swz8(bx, by);
  const int n0 = bx * 128, m0 = by * 128;
  const int tid = threadIdx.x;
  const int lane = tid & 63, wvi = tid >> 6;
  const int wm = (wvi >> 1) * 64, wn = (wvi & 1) * 64;
  const int l15 = lane & 15, quad = lane >> 4;
  const int ib = wvi * 128 + lane;
  const int r0 = ib >> 2, r1 = r0 + 16;
  const int c0 = ((ib & 3) ^ ((r0 >> 1) & 3)) * 8;
  const int c1 = ((ib & 3) ^ ((r1 >> 1) & 3)) * 8;
  const int lb0 = wvi * 1024, lb1 = wvi * 1024 + 512;
  const long ga0 = (long)(m0 + r0) * K + c0;
  const long ga1 = (long)(m0 + r1) * K + c1;
  const long gb0 = (long)(n0 + r0) * K + c0;
  const long gb1 = (long)(n0 + r1) * K + c1;
  f32x4 aM[4][4], aC[4][4];
#pragma unroll
  for (int i = 0; i < 4; i++)
#pragma unroll
    for (int j = 0; j < 4; j++) {
      aM[i][j] = (f32x4){0.f, 0.f, 0.f, 0.f};
      aC[i][j] = (f32x4){0.f, 0.f, 0.f, 0.f};
    }
  // prologue: issue tile 0 (no drain — iter 0's counted wait handles it)
  gld16(Ah + ga0, AsH[0] + lb0);
  gld16(Ah + ga1, AsH[0] + lb1);
  gld16(Al + ga0, AsL[0] + lb0);
  gld16(Al + ga1, AsL[0] + lb1);
  gld16(Bh + gb0, BsH[0] + lb0);
  gld16(Bh + gb1, BsH[0] + lb1);
  gld16(Bl + gb0, BsL[0] + lb0);
  gld16(Bl + gb1, BsL[0] + lb1);
  int cur = 0;
  for (int k0 = 0; k0 < K; k0 += 32) {
    const int kn = k0 + 32;
    if (kn < K) {  // prefetch next tile, then wait only for CURRENT tile
      gld16(Ah + ga0 + kn, AsH[cur ^ 1] + lb0);
      gld16(Ah + ga1 + kn, AsH[cur ^ 1] + lb1);
      gld16(Al + ga0 + kn, AsL[cur ^ 1] + lb0);
      gld16(Al + ga1 + kn, AsL[cur ^ 1] + lb1);
      gld16(Bh + gb0 + kn, BsH[cur ^ 1] + lb0);
      gld16(Bh + gb1 + kn, BsH[cur ^ 1] + lb1);
      gld16(Bl + gb0 + kn, BsL[cur ^ 1] + lb0);
      gld16(Bl + gb1 + kn, BsL[cur ^ 1] + lb1);
      vmwait<8>();
    } else {
      vmwait<0>();
    }
    __builtin_amdgcn_s_barrier();   // tile k complete in LDS (all waves)
    f16x8 fah[4], fal[4], fbh[4], fbl[4];
#pragma unroll
    for (int mi = 0; mi < 4; mi++) {
      int r = wm + mi * 16 + l15;
      int o = r * 32 + ((quad ^ ((r >> 1) & 3)) * 8);
      fah[mi] = *(const f16x8*)&AsH[cur][o];
      fal[mi] = *(const f16x8*)&AsL[cur][o];
    }
#pragma unroll
    for (int ni = 0; ni < 4; ni++) {
      int r = wn + ni * 16 + l15;
      int o = r * 32 + ((quad ^ ((r >> 1) & 3)) * 8);
      fbh[ni] = *(const f16x8*)&BsH[cur][o];
      fbl[ni] = *(const f16x8*)&BsL[cur][o];
    }
#pragma unroll
    for (int mi = 0; mi < 4; mi++)
#pragma unroll
      for (int ni = 0; ni < 4; ni++) {
        aM[mi][ni] = __builtin_amdgcn_mfma_f32_16x16x32_f16(
            fah[mi], fbh[ni], aM[mi][ni], 0, 0, 0);
        aC[mi][ni] = __builtin_amdgcn_mfma_f32_16x16x32_f16(
            fah[mi], fbl[ni], aC[mi][ni], 0, 0, 0);
        aC[mi][ni] = __builtin_amdgcn_mfma_f32_16x16x32_f16(
            fal[mi], fbh[ni], aC[mi][ni], 0, 0, 0);
      }
    __builtin_amdgcn_s_barrier();   // guard buf[cur] before next-iter overwrite
    cur ^= 1;
  }
#pragma unroll
  for (int mi = 0; mi < 4; mi++) {
    int rowg = m0 + wm + mi * 16 + quad * 4;
#pragma unroll
    for (int ni = 0; ni < 4; ni++) {
      int colg = n0 + wn + ni * 16 + l15;
#pragma unroll
      for (int rr = 0; rr < 4; rr++) {
        long off = (long)(rowg + rr) * N + colg;
        float z = aM[mi][ni][rr] + aC[mi][ni][rr] * (1.0f / 512.0f);
        _Float16 zh = (_Float16)z;
        Zh[off] = zh;
        Zl[off] = (_Float16)((z - (float)zh) * 512.0f);
      }
    }
  }
}

// ---------------------------------------------------------------------------
// split-fp16 MFMA Z.X^T + fused wrapped-diagonal mean reduce. BK=32.
// R18: counted-vmcnt pipeline.
// ---------------------------------------------------------------------------
__global__ __launch_bounds__(256) void qkmv_hl(
    const _Float16* __restrict__ Zh, const _Float16* __restrict__ Zl,
    const _Float16* __restrict__ Xh, const _Float16* __restrict__ Xl,
    float* __restrict__ MV) {
  __shared__ __align__(16) _Float16 AsH[2][128 * 32];
  __shared__ __align__(16) _Float16 AsL[2][128 * 32];
  __shared__ __align__(16) _Float16 BsH[2][128 * 32];
  __shared__ __align__(16) _Float16 BsL[2][128 * 32];
  __shared__ float diag[255];
  const int bz = blockIdx.z;
  const long bb = (long)bz * LL * DD;
  const int n0 = blockIdx.x * 128, m0 = blockIdx.y * 128;
  const int tid = threadIdx.x;
  const int lane = tid & 63, wvi = tid >> 6;
  const int wm = (wvi >> 1) * 64, wn = (wvi & 1) * 64;
  const int l15 = lane & 15, quad = lane >> 4;
  const int ib = wvi * 128 + lane;
  const int r0 = ib >> 2, r1 = r0 + 16;
  const int c0 = ((ib & 3) ^ ((r0 >> 1) & 3)) * 8;
  const int c1 = ((ib & 3) ^ ((r1 >> 1) & 3)) * 8;
  const int lb0 = wvi * 1024, lb1 = wvi * 1024 + 512;
  const long ga0 = bb + (long)(m0 + r0) * DD + c0;
  const long ga1 = bb + (long)(m0 + r1) * DD + c1;
  const long gb0 = bb + (long)(n0 + r0) * DD + c0;
  const long gb1 = bb + (long)(n0 + r1) * DD + c1;
  if (tid < 255) diag[tid] = 0.0f;
  f32x4 aM[4][4], aC[4][4];
#pragma unroll
  for (int i = 0; i < 4; i++)
#pragma unroll
    for (int j = 0; j < 4; j++) {
      aM[i][j] = (f32x4){0.f, 0.f, 0.f, 0.f};
      aC[i][j] = (f32x4){0.f, 0.f, 0.f, 0.f};
    }
  // prologue: issue tile 0
  gld16(Zh + ga0, AsH[0] + lb0);
  gld16(Zh + ga1, AsH[0] + lb1);
  gld16(Zl + ga0, AsL[0] + lb0);
  gld16(Zl + ga1, AsL[0] + lb1);
  gld16(Xh + gb0, BsH[0] + lb0);
  gld16(Xh + gb1, BsH[0] + lb1);
  gld16(Xl + gb0, BsL[0] + lb0);
  gld16(Xl + gb1, BsL[0] + lb1);
  int cur = 0;
  for (int k0 = 0; k0 < DD; k0 += 32) {
    const int kn = k0 + 32;
    if (kn < DD) {
      gld16(Zh + ga0 + kn, AsH[cur ^ 1] + lb0);
      gld16(Zh + ga1 + kn, AsH[cur ^ 1] + lb1);
      gld16(Zl + ga0 + kn, AsL[cur ^ 1] + lb0);
      gld16(Zl + ga1 + kn, AsL[cur ^ 1] + lb1);
      gld16(Xh + gb0 + kn, BsH[cur ^ 1] + lb0);
      gld16(Xh + gb1 + kn, BsH[cur ^ 1] + lb1);
      gld16(Xl + gb0 + kn, BsL[cur ^ 1] + lb0);
      gld16(Xl + gb1 + kn, BsL[cur ^ 1] + lb1);
      vmwait<8>();
    } else {
      vmwait<0>();
    }
    __builtin_amdgcn_s_barrier();
    f16x8 fah[4], fal[4], fbh[4], fbl[4];
#pragma unroll
    for (int mi = 0; mi < 4; mi++) {
      int r = wm + mi * 16 + l15;
      int o = r * 32 + ((quad ^ ((r >> 1) & 3)) * 8);
      fah[mi] = *(const f16x8*)&AsH[cur][o];
      fal[mi] = *(const f16x8*)&AsL[cur][o];
    }
#pragma unroll
    for (int ni = 0; ni < 4; ni++) {
      int r = wn + ni * 16 + l15;
      int o = r * 32 + ((quad ^ ((r >> 1) & 3)) * 8);
      fbh[ni] = *(const f16x8*)&BsH[cur][o];
      fbl[ni] = *(const f16x8*)&BsL[cur][o];
    }
#pragma unroll
    for (int mi = 0; mi < 4; mi++)
#pragma unroll
      for (int ni = 0; ni < 4; ni++) {
        aM[mi][ni] = __builtin_amdgcn_mfma_f32_16x16x32_f16(
            fah[mi], fbh[ni], aM[mi][ni], 0, 0, 0);
        aC[mi][ni] = __builtin_amdgcn_mfma_f32_16x16x32_f16(
            fah[mi], fbl[ni], aC[mi][ni], 0, 0, 0);
        aC[mi][ni] = __builtin_amdgcn_mfma_f32_16x16x32_f16(
            fal[mi], fbh[ni], aC[mi][ni], 0, 0, 0);
      }
    __builtin_amdgcn_s_barrier();
    cur ^= 1;
  }
#pragma unroll
  for (int g = -3; g <= 3; g++) {
#pragma unroll
    for (int rr = 0; rr < 4; rr++) {
      float s = 0.0f;
#pragma unroll
      for (int mi = 0; mi < 4; mi++) {
        int ni = mi - g;
        if (ni >= 0 && ni < 4)
          s += aM[mi][ni][rr] + aC[mi][ni][rr] * (1.0f / 512.0f);
      }
      int d = 127 + (wm - wn) + g * 16 + quad * 4 + rr - l15;
      atomicAdd(&diag[d], s);
    }
  }
  __syncthreads();
  if (tid < 255) {
    int tau = (m0 - n0 + tid - 127 + LL) & (LL - 1);
    atomicAdd(&MV[(long)bz * LL + tau], diag[tid] * (1.0f / 512.0f));
  }
}

// ---------------------------------------------------------------------------
// fp16 MFMA GEMM: C[M,N] = act( A[M,K] @ W[N,K]^T + bias + R )
// R19: tile 128x64, waves 2x2 (64x32 each), BK=32, counted-vmcnt pipeline
// (3 loads/tile in flight). LDS 24KB. Grid = (N/64, M/128).
// FLAGS: 1=bias 2=gelu 4=residual 8=out-fp16
// ---------------------------------------------------------------------------
template <int FLAGS>
__global__ __launch_bounds__(256) void gemm_h(
    const _Float16* __restrict__ A, const _Float16* __restrict__ W,
    const void* __restrict__ biasBase, long bOff,
    const float* __restrict__ R, void* __restrict__ Cout,
    int M, int N, int K, const int* __restrict__ FLAG) {
  constexpr bool HAS_BIAS = (FLAGS & 1) != 0;
  constexpr bool DO_GELU = (FLAGS & 2) != 0;
  constexpr bool DO_RES = (FLAGS & 4) != 0;
  constexpr bool OUT_H = (FLAGS & 8) != 0;
  __shared__ __align__(16) _Float16 As[2][128 * 32];
  __shared__ __align__(16) _Float16 Bs[2][64 * 32];
  int bx = blockIdx.x, by = blockIdx.y;
  swz8(bx, by);
  const int n0 = bx * 64, m0 = by * 128;
  const int tid = threadIdx.x;
  const int lane = tid & 63, wvi = tid >> 6;
  const int wm = (wvi >> 1) * 64, wn = (wvi & 1) * 32;
  const int l15 = lane & 15, quad = lane >> 4;
  // A staging (identical to verified 128-row pattern): 2 gld16/thread
  const int ib = wvi * 128 + lane;
  const int r0 = ib >> 2, r1 = r0 + 16;
  const int c0 = ((ib & 3) ^ ((r0 >> 1) & 3)) * 8;
  const int c1 = ((ib & 3) ^ ((r1 >> 1) & 3)) * 8;
  const int lbA0 = wvi * 1024, lbA1 = wvi * 1024 + 512;
  const long ga0 = (long)(m0 + r0) * K + c0;
  const long ga1 = (long)(m0 + r1) * K + c1;
  // B staging: 64 rows, 256 slots (1 gld16/thread), same XOR-seg pattern
  const int jb = tid;
  const int rB = jb >> 2;
  const int cB = ((jb & 3) ^ ((rB >> 1) & 3)) * 8;
  const int lbB = wvi * 512;
  const long gb0 = (long)(n0 + rB) * K + cB;
  f32x4 acc[4][2];
#pragma unroll
  for (int i = 0; i < 4; i++)
#pragma unroll
    for (int j = 0; j < 2; j++) acc[i][j] = (f32x4){0.f, 0.f, 0.f, 0.f};
  // prologue: issue tile 0
  gld16(A + ga0, As[0] + lbA0);
  gld16(A + ga1, As[0] + lbA1);
  gld16(W + gb0, Bs[0] + lbB);
  int cur = 0;
  for (int k0 = 0; k0 < K; k0 += 32) {
    const int kn = k0 + 32;
    if (kn < K) {  // prefetch next tile, wait only for current
      gld16(A + ga0 + kn, As[cur ^ 1] + lbA0);
      gld16(A + ga1 + kn, As[cur ^ 1] + lbA1);
      gld16(W + gb0 + kn, Bs[cur ^ 1] + lbB);
      vmwait<3>();
    } else {
      vmwait<0>();
    }
    __builtin_amdgcn_s_barrier();
    f16x8 af[4], bfr[2];
#pragma unroll
    for (int mi = 0; mi < 4; mi++) {
      int r = wm + mi * 16 + l15;
      int o = r * 32 + ((quad ^ ((r >> 1) & 3)) * 8);
      af[mi] = *(const f16x8*)&As[cur][o];
    }
#pragma unroll
    for (int ni = 0; ni < 2; ni++) {
      int r = wn + ni * 16 + l15;
      int o = r * 32 + ((quad ^ ((r >> 1) & 3)) * 8);
      bfr[ni] = *(const f16x8*)&Bs[cur][o];
    }
#pragma unroll
    for (int mi = 0; mi < 4; mi++)
#pragma unroll
      for (int ni = 0; ni < 2; ni++)
        acc[mi][ni] = __builtin_amdgcn_mfma_f32_16x16x32_f16(
            af[mi], bfr[ni], acc[mi][ni], 0, 0, 0);
    __builtin_amdgcn_s_barrier();
    cur ^= 1;
  }
  float bcol[2];
  if constexpr (HAS_BIAS) {
    const int isf = *FLAG;
#pragma unroll
    for (int ni = 0; ni < 2; ni++)
      bcol[ni] = ldi(biasBase, bOff + n0 + wn + ni * 16 + l15, isf);
  }
#pragma unroll
  for (int mi = 0; mi < 4; mi++) {
    int rowg = m0 + wm + mi * 16 + quad * 4;
#pragma unroll
    for (int ni = 0; ni < 2; ni++) {
      int colg = n0 + wn + ni * 16 + l15;
#pragma unroll
      for (int rr = 0; rr < 4; rr++) {
        long off = (long)(rowg + rr) * N + colg;
        float v = acc[mi][ni][rr];
        if constexpr (HAS_BIAS) v += bcol[ni];
        if constexpr (DO_RES) v += R[off];
        if constexpr (DO_GELU) v = gelu_f(v);
        if constexpr (OUT_H) ((_Float16*)Cout)[off] = (_Float16)v;
        else ((float*)Cout)[off] = v;
      }
    }
  }
}

// ---------------------------------------------------------------------------
// top-6 of MV[b,:] + softmax.  grid (32), block 256
// ---------------------------------------------------------------------------
__global__ __launch_bounds__(256) void topk_k(const float* __restrict__ MV,
                                              float* __restrict__ WGT,
                                              int* __restrict__ DLY) {
  int b = blockIdx.x;
  __shared__ float vals[LL];
  __shared__ float rv[256];
  __shared__ int ri[256];
  __shared__ float selv[6];
  int tid = threadIdx.x;
  for (int i = tid; i < LL; i += 256) vals[i] = MV[(long)b * LL + i];
  __syncthreads();
  for (int it = 0; it < 6; it++) {
    float bv = -1e30f;
    int bi = LL - 1;
    for (int i = tid; i < LL; i += 256) {
      float v = vals[i];
      if (v > bv || (v == bv && i < bi)) { bv = v; bi = i; }
    }
    rv[tid] = bv; ri[tid] = bi;
    __syncthreads();
    for (int st = 128; st > 0; st >>= 1) {
      if (tid < st) {
        float ov = rv[tid + st]; int oi = ri[tid + st];
        if (ov > rv[tid] || (ov == rv[tid] && oi < ri[tid])) {
          rv[tid] = ov; ri[tid] = oi;
        }
      }
      __syncthreads();
    }
    if (tid == 0) {
      selv[it] = rv[0];
      DLY[b * 6 + it] = ri[0];
      vals[ri[0]] = -1e30f;
    }
    __syncthreads();
  }
  if (tid == 0) {
    float mx = selv[0];
    float e[6], s = 0.0f;
    for (int i = 0; i < 6; i++) { e[i] = expf(selv[i] - mx); s += e[i]; }
    for (int i = 0; i < 6; i++) WGT[b * 6 + i] = e[i] / s;
  }
}

// ---------------------------------------------------------------------------
// time-delay aggregation, fp16 in/out (chunk-local): grid (1024, NB), block 128
// ---------------------------------------------------------------------------
__global__ __launch_bounds__(128) void agg_k(const _Float16* __restrict__ V,
                                             const float* __restrict__ WGT,
                                             const int* __restrict__ DLY,
                                             _Float16* __restrict__ O) {
  int l = blockIdx.x, b = blockIdx.y;
  int tid = threadIdx.x;
  float w[6]; int dl[6];
#pragma unroll
  for (int i = 0; i < 6; i++) { w[i] = WGT[b * 6 + i]; dl[i] = DLY[b * 6 + i]; }
  long base = (long)b * LL * DD;
  int d = tid * 4;
  float a0 = 0, a1 = 0, a2 = 0, a3 = 0;
#pragma unroll
  for (int i = 0; i < 6; i++) {
    int row = (l + dl[i]) & (LL - 1);
    H4 t; t.u = *(const uint2*)&V[base + (long)row * DD + d];
    a0 += w[i] * (float)t.h[0];
    a1 += w[i] * (float)t.h[1];
    a2 += w[i] * (float)t.h[2];
    a3 += w[i] * (float)t.h[3];
  }
  H4 r;
  r.h[0] = (_Float16)a0; r.h[1] = (_Float16)a1;
  r.h[2] = (_Float16)a2; r.h[3] = (_Float16)a3;
  *(uint2*)&O[base + (long)l * DD + d] = r.u;
}

// ---------------------------------------------------------------------------
// series_decomp residual (f32 out only, race-free). grid (2, 16, 32), block 256
// ---------------------------------------------------------------------------
__global__ __launch_bounds__(256) void decomp_k(const float* __restrict__ Xin,
                                                float* __restrict__ Out) {
  int d = blockIdx.x * 256 + threadIdx.x;
  int l0 = blockIdx.y * 64;
  int b = blockIdx.z;
  const float* xb = Xin + (long)b * LL * DD + d;
  float* ob = Out + (long)b * LL * DD + d;
  float wsum = 0.0f;
  for (int j = l0 - 12; j <= l0 + 12; j++) {
    int jj = min(max(j, 0), LL - 1);
    wsum += xb[(long)jj * DD];
  }
  for (int l = l0; l < l0 + 64; l++) {
    float xv = xb[(long)l * DD];
    ob[(long)l * DD] = xv - wsum * (1.0f / 25.0f);
    int ja = min(l + 13, LL - 1);
    int jr = max(l - 12, 0);
    wsum += xb[(long)ja * DD] - xb[(long)jr * DD];
  }
}

// special layernorm. grid (1024,32), block 256
__global__ __launch_bounds__(256) void ln_k(const float* __restrict__ X,
                                            const void* __restrict__ g,
                                            const void* __restrict__ be,
                                            float* __restrict__ XHo,
                                            const int* __restrict__ FLAG) {
  const int isf = *FLAG;
  int l = blockIdx.x, b = blockIdx.y;
  const float* xr = X + ((long)b * LL + l) * DD;
  int tid = threadIdx.x;
  float x0 = xr[tid], x1 = xr[tid + 256];
  __shared__ float rs[256], rq[256];
  rs[tid] = x0 + x1;
  rq[tid] = x0 * x0 + x1 * x1;
  __syncthreads();
  for (int st = 128; st > 0; st >>= 1) {
    if (tid < st) { rs[tid] += rs[tid + st]; rq[tid] += rq[tid + st]; }
    __syncthreads();
  }
  float mu = rs[0] * (1.0f / 512.0f);
  float var = rq[0] * (1.0f / 512.0f) - mu * mu;
  float rstd = rsqrtf(var + 1e-5f);
  float* o = XHo + ((long)b * LL + l) * DD;
  o[tid] = (x0 - mu) * rstd * ldi(g, tid, isf) + ldi(be, tid, isf);
  o[tid + 256] = (x1 - mu) * rstd * ldi(g, tid + 256, isf) + ldi(be, tid + 256, isf);
}

// column-mean partials. grid (2, 8, 32), block 256: part sums 128 rows.
__global__ __launch_bounds__(256) void colmean_k(const float* __restrict__ XHo,
                                                 float* __restrict__ CMp) {
  int d = blockIdx.x * 256 + threadIdx.x;
  int part = blockIdx.y;
  int b = blockIdx.z;
  const float* p = XHo + (long)b * LL * DD + (long)part * 128 * DD + d;
  float s = 0.0f;
  for (int l = 0; l < 128; l++) s += p[(long)l * DD];
  CMp[((long)part * BB + b) * DD + d] = s;
}

// OUT = gelu(XH - mean) * mark. grid (1024,32), block 256
__global__ __launch_bounds__(256) void geluout_k(const float* __restrict__ XHo,
                                                 const float* __restrict__ CMp,
                                                 const void* __restrict__ mark,
                                                 float* __restrict__ OUT,
                                                 const int* __restrict__ FLAG) {
  const int isf = *FLAG;
  int l = blockIdx.x, b = blockIdx.y;
  int tid = threadIdx.x;
  float mk = ldi(mark, (long)b * LL + l, isf);
  long off = ((long)b * LL + l) * DD;
#pragma unroll
  for (int h = 0; h < 2; h++) {
    int d = tid + h * 256;
    float cs = 0.0f;
#pragma unroll
    for (int p = 0; p < 8; p++) cs += CMp[((long)p * BB + b) * DD + d];
    float v = XHo[off + d] - cs * (1.0f / 1024.0f);
    OUT[off + d] = gelu_f(v) * mk;
  }
}

// ---------------------------------------------------------------------------
// proj stage 1 v2: read-once split-K. grid (512), block 256.
// ---------------------------------------------------------------------------
__global__ __launch_bounds__(256) void proj1_k(const float* __restrict__ OUT,
                                               const void* __restrict__ Wp,
                                               float* __restrict__ PB2,
                                               const int* __restrict__ FLAG) {
  const int isf = *FLAG;
  const int blk = blockIdx.x;
  const int tid = threadIdx.x;
  const int wave = tid >> 6, lane = tid & 63;
  const int grp = lane >> 4, ln = lane & 15;
  const long e = (long)blk * 1024 + tid * 4;
  float w[10][4];
  if (isf) {
    const float* wp = (const float*)Wp;
#pragma unroll
    for (int n = 0; n < 10; n++) {
      float4 t = *(const float4*)&wp[(long)n * 524288 + e];
      w[n][0] = t.x; w[n][1] = t.y; w[n][2] = t.z; w[n][3] = t.w;
    }
  } else {
    const u16* wp = (const u16*)Wp;
#pragma unroll
    for (int n = 0; n < 10; n++) {
      uint2 u = *(const uint2*)&wp[(long)n * 524288 + e];
      w[n][0] = bf2f((u16)(u.x & 0xffff));
      w[n][1] = bf2f((u16)(u.x >> 16));
      w[n][2] = bf2f((u16)(u.y & 0xffff));
      w[n][3] = bf2f((u16)(u.y >> 16));
    }
  }
  __shared__ float sm[4][4][BB][16];  // [wave][grp][b][n] = 32 KB
  float4 xn = *(const float4*)&OUT[e];  // prefetch b=0
  for (int b = 0; b < BB; b++) {
    float4 x = xn;
    if (b < BB - 1) xn = *(const float4*)&OUT[(long)(b + 1) * 524288 + e];
    float acc[10];
#pragma unroll
    for (int n = 0; n < 10; n++)
      acc[n] = x.x * w[n][0] + x.y * w[n][1] + x.z * w[n][2] + x.w * w[n][3];
#pragma unroll
    for (int s = 1; s <= 8; s <<= 1)
#pragma unroll
      for (int n = 0; n < 10; n++) acc[n] += __shfl_xor(acc[n], s, 64);
    float v = 0.0f;
#pragma unroll
    for (int n = 0; n < 10; n++) v = (ln == n) ? acc[n] : v;
    if (ln < 10) sm[wave][grp][b][ln] = v;
  }
  __syncthreads();
  for (int o = tid; o < BB * 10; o += 256) {
    int b = o / 10, n = o - b * 10;
    float s = 0.0f;
#pragma unroll
    for (int w4 = 0; w4 < 4; w4++)
#pragma unroll
      for (int g = 0; g < 4; g++) s += sm[w4][g][b][n];
    PB2[(long)o * 512 + blk] = s;
  }
}

// proj stage 2 v2: reduce 512 partials per (b,n). grid (10,32), block 64
__global__ __launch_bounds__(64) void proj2_k(const float* __restrict__ PB2,
                                              const void* __restrict__ bp,
                                              void* __restrict__ out,
                                              const int* __restrict__ FLAG) {
  const int isf = *FLAG;
  int n = blockIdx.x, b = blockIdx.y;
  int o = b * 10 + n;
  int tid = threadIdx.x;
  float s = 0.0f;
  for (int j = tid; j < 512; j += 64) s += PB2[(long)o * 512 + j];
#pragma unroll
  for (int st = 32; st > 0; st >>= 1) s += __shfl_xor(s, st, 64);
  if (tid == 0) {
    s += ldi(bp, n, isf);
    if (isf) ((float*)out)[o] = s;
    else ((u16*)out)[o] = f2bf(s);
  }
}

// ---------------------------------------------------------------------------
extern "C" void kernel_launch(void* const* d_in, const int* in_sizes, int n_in,
                              void* d_out, int out_size, void* d_ws, size_t ws_size,
                              hipStream_t stream) {
  const void* xe = d_in[0];
  const void* mark = d_in[1];
  const void* cw = d_in[2];
  const void* Wq = d_in[3];
  const void* Wk = d_in[5];
  const void* Wv = d_in[7];
  const void* bv = d_in[8];
  const void* Wo = d_in[9];
  const void* bo = d_in[10];
  const void* Wff1 = d_in[11];
  const void* Wff2 = d_in[12];
  const void* lng = d_in[13];
  const void* lnb = d_in[14];
  const void* Wp = d_in[15];
  const void* bp = d_in[16];

  char* ws = (char*)d_ws;
  float* X      = (float*)(ws + 0L);               // 64 MiB f32 residual
  _Float16* XH  = (_Float16*)(ws + 67108864L);     // fp16 X-high, 32 MiB
  _Float16* XL  = (_Float16*)(ws + 100663296L);    // fp16 X-low*512 / AGh
  _Float16* AGh = (_Float16*)(ws + 100663296L);
  _Float16* ZH  = (_Float16*)(ws + 134217728L);    // Z-high chunk, 4 MiB
  _Float16* ZL  = (_Float16*)(ws + 138412032L);    // Z-low chunk, 4 MiB
  _Float16* Ph  = (_Float16*)(ws + 134217728L);    // Phase B: 8 MiB chunk
  float* CMp    = (float*)(ws + 134217728L);       // final: colmean partials
  float* wT     = (float*)(ws + 142606336L);       // conv wT (dead after embed)
  // Phase A overlays (all dead by Phase B):
  _Float16* KTH = (_Float16*)(ws + 142606336L);    // Wk^T split hi, 0.5 MiB
  _Float16* KTL = (_Float16*)(ws + 143130624L);    // Wk^T split lo
  _Float16* QTH = (_Float16*)(ws + 143654912L);    // Wq^T split hi
  _Float16* QTL = (_Float16*)(ws + 144179200L);    // Wq^T split lo
  _Float16* GH  = (_Float16*)(ws + 144703488L);    // G split hi, 0.5 MiB
  _Float16* GL  = (_Float16*)(ws + 145227776L);    // G split lo
  // Phase B overlays:
  _Float16* Wvh = (_Float16*)(ws + 142606336L);
  _Float16* Woh = (_Float16*)(ws + 143130624L);
  _Float16* W1h = (_Float16*)(ws + 143654912L);    // 2 MiB
  _Float16* W2h = (_Float16*)(ws + 145752064L);    // 2 MiB
  float* MV  = (float*)(ws + 147849216L);
  float* WGT = (float*)(ws + 147980288L);
  int*   DLY = (int*)(ws + 147981312L);
  int*  FLAG = (int*)(ws + 148068352L);
  float* S2  = (float*)(ws + 67108864L);           // FFN f32 (spans XH+XL)
  float* PB2 = (float*)(ws + 67108864L);           // proj partials (S2 dead)
  _Float16* Hb = (_Float16*)X;                     // FFN hidden (X dead)

  const long AD = (long)LL * DD;   // 524288
  const int M = BB * LL;           // 32768

  detect_k<<<1, 64, 0, stream>>>((const uint32_t*)mark, FLAG);
  wT_k<<<126, 256, 0, stream>>>(cw, wT, FLAG);
  conv_embed_k<<<dim3(64, 32), 256, 0, stream>>>(xe, wT, X, XH, XL, FLAG);

  for (int l = 0; l < 3; l++) {
    const long oW = (long)l * DD * DD;
    const long oB = (long)l * DD;
    const long oF = (long)l * DFF * DD;

    // ---- Phase A: delay selection via G-trick + fp16x2 split MFMA ----
    tsplit2_k<<<dim3(8, 8, 2), 256, 0, stream>>>(Wk, Wq, oW,
                                                 KTH, KTL, QTH, QTL, FLAG);
    gemm_z<<<dim3(4, 4), 256, 0, stream>>>(KTH, KTL, QTH, QTL,
                                           GH, GL, 512, 512, 512);
    hipMemsetAsync(MV, 0, (long)BB * LL * sizeof(float), stream);
    for (int cb = 0; cb < 8; cb++) {
      const long co = (long)cb * 4 * AD;
      gemm_z<<<dim3(4, 32), 256, 0, stream>>>(
          XH + co, XL + co, GH, GL, ZH, ZL, 4096, DD, DD);
      qkmv_hl<<<dim3(8, 8, 4), 256, 0, stream>>>(
          ZH, ZL, XH + co, XL + co, MV + (long)cb * 4 * LL);
    }
    topk_k<<<32, 256, 0, stream>>>(MV, WGT, DLY);

    // ---- Phase B: fp16 MFMA for V / agg / Wo / FFN ----
    wcvt6_k<<<1280, 256, 0, stream>>>(Wv, Wo, Wff1, Wff2, oW, oF,
                                      Wvh, Woh, W1h, W2h, FLAG);

    // V (fp16) per 8-batch chunk -> Ph (over ZH/ZL, dead), agg -> AGh
    for (int cb = 0; cb < 4; cb++) {
      const _Float16* xh = XH + (long)cb * 8 * AD;
      gemm_h<1 | 8><<<dim3(8, 64), 256, 0, stream>>>(
          xh, Wvh, bv, oB, nullptr, Ph, 8192, DD, DD, FLAG);
      agg_k<<<dim3(1024, 8), 128, 0, stream>>>(
          Ph, WGT + cb * 48, DLY + cb * 48, AGh + (long)cb * 8 * AD);
    }

    // X = X + AGh @ Wo^T + bo (full M, in-place residual)
    gemm_h<1 | 4><<<dim3(8, 256), 256, 0, stream>>>(
        AGh, Woh, bo, oB, X, X, M, DD, DD, FLAG);

    // x = decomp(X) -> S2 f32 (over XH/XL, both dead)
    decomp_k<<<dim3(2, 16, 32), 256, 0, stream>>>(X, S2);

    // FFN per 8-batch chunk: S2 chunk -> fp16 Ph; hidden -> Hb (X region);
    // S2chunk = S2chunk + (gelu-hidden) @ W2^T
    for (int cb = 0; cb < 4; cb++) {
      float* xd = S2 + (long)cb * 8 * AD;
      acvt_k<<<2048, 256, 0, stream>>>(xd, Ph, 4194304);
      gemm_h<2 | 8><<<dim3(32, 64), 256, 0, stream>>>(
          Ph, W1h, nullptr, 0, nullptr, Hb, 8192, DFF, DD, FLAG);
      gemm_h<4><<<dim3(8, 64), 256, 0, stream>>>(
          Hb, W2h, nullptr, 0, xd, xd, 8192, DD, DFF, FLAG);
    }

    // x = decomp(S2) -> X; then split X -> (XH, XL) for next layer
    decomp_k<<<dim3(2, 16, 32), 256, 0, stream>>>(S2, X);
    if (l < 2) split_k<<<8192, 256, 0, stream>>>(X, XH, XL, 16777216);
  }

  // final special layernorm + gelu + mask + projection
  ln_k<<<dim3(1024, 32), 256, 0, stream>>>(X, lng, lnb, S2, FLAG);
  colmean_k<<<dim3(2, 8, 32), 256, 0, stream>>>(S2, CMp);
  geluout_k<<<dim3(1024, 32), 256, 0, stream>>>(S2, CMp, mark, X, FLAG);
  proj1_k<<<512, 256, 0, stream>>>(X, Wp, PB2, FLAG);
  proj2_k<<<dim3(10, 32), 64, 0, stream>>>(PB2, bp, d_out, FLAG);
}

// Round 11
// 3100.746 us; speedup vs baseline: 1.1108x; 1.0611x over previous
//
#include <hip/hip_runtime.h>
#include <cstdint>

// ---------------------------------------------------------------------------
// Autoformer forward — hybrid precision v15 (R20):
//   * R20: gemm_z tile 64x64 (was 128x128): 4 waves of 32x32, acc[2][2] per
//     split array, 4 gld16/tile + vmcnt(4), LDS 32KB (was 64KB). Chunk grid
//     (4,32)=128 blocks (0.5/CU, half GPU idle) -> (8,64)=512 (2/CU).
//     Staging = R19's verified 64-row XOR-seg pattern; fragment read
//     formula unchanged. qkmv left untouched (diag math coupled to 128
//     geometry).
//   * R19: gemm_h tile 128x64 (verified −83us; Wo occ 9->31%).
//   * R18: counted-vmcnt pipeline.  * R17: FFN1 = acvt + fp16 gemm_h.
//   * R16: 2-phase K-loop (−183us).  * R15: XCD swizzle.
//   * R14a/R13/R11: conv reg-cache, proj v2, tsplit2.
// Inputs f32 (runtime-detected from x_mark_enc; bf16 fallback kept).
// Workspace map: see v12 header (unchanged).
// ---------------------------------------------------------------------------

using u16 = unsigned short;
typedef _Float16 f16x8 __attribute__((ext_vector_type(8)));
typedef float f32x4 __attribute__((ext_vector_type(4)));

#define BB 32
#define LL 1024
#define DD 512
#define DFF 2048

__device__ __forceinline__ float bf2f(u16 u) {
  union { uint32_t i; float f; } v; v.i = ((uint32_t)u) << 16; return v.f;
}
__device__ __forceinline__ u16 f2bf(float f) {
  union { float f; uint32_t i; } v; v.f = f;
  uint32_t r = (v.i + 0x7FFFu + ((v.i >> 16) & 1u)) >> 16;
  return (u16)r;
}
__device__ __forceinline__ float ldi(const void* p, long i, int isf) {
  return isf ? ((const float*)p)[i] : bf2f(((const u16*)p)[i]);
}
__device__ __forceinline__ float gelu_f(float x) {
  return 0.5f * x * (1.0f + erff(x * 0.70710678118654752440f));
}
// async 16B global -> LDS (wave-uniform LDS base + lane*16)
__device__ __forceinline__ void gld16(const void* g, void* l) {
  __builtin_amdgcn_global_load_lds(
      (const __attribute__((address_space(1))) void*)g,
      (__attribute__((address_space(3))) void*)l, 16, 0, 0);
}
// counted vmcnt wait (immediate) — leaves N newest VMEM ops in flight
template <int N>
__device__ __forceinline__ void vmwait() {
  if constexpr (N == 0) asm volatile("s_waitcnt vmcnt(0)" ::: "memory");
  else if constexpr (N == 3) asm volatile("s_waitcnt vmcnt(3)" ::: "memory");
  else if constexpr (N == 4) asm volatile("s_waitcnt vmcnt(4)" ::: "memory");
  else asm volatile("s_waitcnt vmcnt(8)" ::: "memory");
}
// XCD-aware bijective block swizzle (requires nwg % 8 == 0, all grids comply)
__device__ __forceinline__ void swz8(int& bx, int& by) {
  int gx = gridDim.x;
  int nwg = gx * gridDim.y;
  int bid = by * gx + bx;
  int q = nwg >> 3;
  int s = (bid & 7) * q + (bid >> 3);
  bx = s % gx;
  by = s / gx;
}

union H8 { f16x8 v; uint4 u; _Float16 h[8]; };
union H4 { uint2 u; _Float16 h[4]; };

__global__ void detect_k(const uint32_t* __restrict__ mark, int* __restrict__ FLAG) {
  if (threadIdx.x == 0) FLAG[0] = (mark[0] == 0x3F800000u) ? 1 : 0;
}

// transpose conv weight to wT[(c*3+t)*512 + d], f32. grid 126, block 256
__global__ __launch_bounds__(256) void wT_k(const void* __restrict__ w,
                                            float* __restrict__ wT,
                                            const int* __restrict__ FLAG) {
  const int isf = *FLAG;
  int idx = blockIdx.x * 256 + threadIdx.x;
  if (idx >= 63 * DD) return;
  int c3t = idx / DD;
  int d = idx - c3t * DD;
  wT[idx] = ldi(w, (long)d * 63 + c3t, isf);
}

// ---------------------------------------------------------------------------
// Conv1d circular embedding + fused split. grid (L/16, B), block 256.
// ---------------------------------------------------------------------------
__global__ __launch_bounds__(256) void conv_embed_k(
    const void* __restrict__ xe, const float* __restrict__ wT,
    float* __restrict__ X, _Float16* __restrict__ XH, _Float16* __restrict__ XL,
    const int* __restrict__ FLAG) {
  const int isf = *FLAG;
  int b = blockIdx.y;
  int l0 = blockIdx.x * 16;
  __shared__ float xs[18][21];
  int tid = threadIdx.x;
  for (int i = tid; i < 18 * 21; i += 256) {
    int r = i / 21, c = i % 21;
    int row = (l0 - 1 + r + LL) & (LL - 1);
    xs[r][c] = ldi(xe, ((long)b * LL + row) * 21 + c, isf);
  }
  __syncthreads();
  float acc0[16], acc1[16];
#pragma unroll
  for (int ll = 0; ll < 16; ll++) { acc0[ll] = 0.0f; acc1[ll] = 0.0f; }
  for (int c = 0; c < 21; c++) {
    float xreg[18];
#pragma unroll
    for (int r = 0; r < 18; r++) xreg[r] = xs[r][c];
#pragma unroll
    for (int t = 0; t < 3; t++) {
      float w0 = wT[(c * 3 + t) * DD + tid];
      float w1 = wT[(c * 3 + t) * DD + tid + 256];
#pragma unroll
      for (int ll = 0; ll < 16; ll++) {
        acc0[ll] = fmaf(w0, xreg[t + ll], acc0[ll]);
        acc1[ll] = fmaf(w1, xreg[t + ll], acc1[ll]);
      }
    }
  }
#pragma unroll
  for (int ll = 0; ll < 16; ll++) {
    long base = ((long)b * LL + l0 + ll) * DD;
    float v0 = acc0[ll], v1 = acc1[ll];
    X[base + tid] = v0;
    X[base + tid + 256] = v1;
    _Float16 h0 = (_Float16)v0, h1 = (_Float16)v1;
    XH[base + tid] = h0;
    XH[base + tid + 256] = h1;
    XL[base + tid] = (_Float16)((v0 - (float)h0) * 512.0f);
    XL[base + tid + 256] = (_Float16)((v1 - (float)h1) * 512.0f);
  }
}

// ---------------------------------------------------------------------------
// transpose + split BOTH Wq/Wk in one launch. grid (8, 8, 2), block 256.
// ---------------------------------------------------------------------------
__global__ __launch_bounds__(256) void tsplit2_k(
    const void* __restrict__ W1, const void* __restrict__ W2, long off,
    _Float16* __restrict__ T1H, _Float16* __restrict__ T1L,
    _Float16* __restrict__ T2H, _Float16* __restrict__ T2L,
    const int* __restrict__ FLAG) {
  const int isf = *FLAG;
  const void* W = blockIdx.z ? W2 : W1;
  _Float16* TH = blockIdx.z ? T2H : T1H;
  _Float16* TL = blockIdx.z ? T2L : T1L;
  __shared__ float t[64][65];
  const int f0 = blockIdx.x * 64, m0 = blockIdx.y * 64;
  const int tid = threadIdx.x;
  const int c = tid & 63, rb = tid >> 6;
#pragma unroll
  for (int r = rb; r < 64; r += 4)
    t[r][c] = ldi(W, off + (long)(f0 + r) * DD + m0 + c, isf);
  __syncthreads();
#pragma unroll
  for (int r = rb; r < 64; r += 4) {
    float v = t[c][r];
    long o = (long)(m0 + r) * DD + f0 + c;
    _Float16 hv = (_Float16)v;
    TH[o] = hv;
    TL[o] = (_Float16)((v - (float)hv) * 512.0f);
  }
}

// split f32 -> (fp16 high, fp16 low*512). 8 elems/thread.
__global__ __launch_bounds__(256) void split_k(const float* __restrict__ src,
                                               _Float16* __restrict__ dh,
                                               _Float16* __restrict__ dl, int n) {
  long i = ((long)blockIdx.x * 256 + threadIdx.x) * 8;
  if (i >= n) return;
  float4 a = *(const float4*)(src + i);
  float4 b = *(const float4*)(src + i + 4);
  float x[8] = {a.x, a.y, a.z, a.w, b.x, b.y, b.z, b.w};
  H8 h, l;
#pragma unroll
  for (int j = 0; j < 8; j++) {
    _Float16 hv = (_Float16)x[j];
    h.h[j] = hv;
    l.h[j] = (_Float16)((x[j] - (float)hv) * 512.0f);
  }
  *(uint4*)(dh + i) = h.u;
  *(uint4*)(dl + i) = l.u;
}

// convert f32 -> fp16 (plain), 8 elems/thread
__global__ __launch_bounds__(256) void acvt_k(const float* __restrict__ src,
                                              _Float16* __restrict__ dst, int n) {
  long i = ((long)blockIdx.x * 256 + threadIdx.x) * 8;
  if (i >= n) return;
  float4 a = *(const float4*)(src + i);
  float4 b = *(const float4*)(src + i + 4);
  H8 r;
  r.h[0] = (_Float16)a.x; r.h[1] = (_Float16)a.y;
  r.h[2] = (_Float16)a.z; r.h[3] = (_Float16)a.w;
  r.h[4] = (_Float16)b.x; r.h[5] = (_Float16)b.y;
  r.h[6] = (_Float16)b.z; r.h[7] = (_Float16)b.w;
  *(uint4*)(dst + i) = r.u;
}

// all four Phase-B weights -> fp16 in one launch. grid 1280, block 256
__global__ __launch_bounds__(256) void wcvt6_k(
    const void* __restrict__ Wv, const void* __restrict__ Wo,
    const void* __restrict__ W1, const void* __restrict__ W2,
    long oW, long oF,
    _Float16* __restrict__ Wvh, _Float16* __restrict__ Woh,
    _Float16* __restrict__ W1h, _Float16* __restrict__ W2h,
    const int* __restrict__ FLAG) {
  const int isf = *FLAG;
  long e = ((long)blockIdx.x * 256 + threadIdx.x) * 8;
  const void* src; long soff; _Float16* dst;
  if (e < 262144) { src = Wv; soff = oW + e; dst = Wvh + e; }
  else if (e < 524288) { src = Wo; soff = oW + (e - 262144); dst = Woh + (e - 262144); }
  else if (e < 1572864) { src = W1; soff = oF + (e - 524288); dst = W1h + (e - 524288); }
  else { src = W2; soff = oF + (e - 1572864); dst = W2h + (e - 1572864); }
  H8 r;
  if (isf) {
    const float* s = (const float*)src + soff;
    float4 a = *(const float4*)s;
    float4 b = *(const float4*)(s + 4);
    r.h[0] = (_Float16)a.x; r.h[1] = (_Float16)a.y;
    r.h[2] = (_Float16)a.z; r.h[3] = (_Float16)a.w;
    r.h[4] = (_Float16)b.x; r.h[5] = (_Float16)b.y;
    r.h[6] = (_Float16)b.z; r.h[7] = (_Float16)b.w;
  } else {
    const u16* s = (const u16*)src + soff;
    uint4 u = *(const uint4*)s;
    r.h[0] = (_Float16)bf2f((u16)(u.x & 0xffff));
    r.h[1] = (_Float16)bf2f((u16)(u.x >> 16));
    r.h[2] = (_Float16)bf2f((u16)(u.y & 0xffff));
    r.h[3] = (_Float16)bf2f((u16)(u.y >> 16));
    r.h[4] = (_Float16)bf2f((u16)(u.z & 0xffff));
    r.h[5] = (_Float16)bf2f((u16)(u.z >> 16));
    r.h[6] = (_Float16)bf2f((u16)(u.w & 0xffff));
    r.h[7] = (_Float16)bf2f((u16)(u.w >> 16));
  }
  *(uint4*)(dst) = r.u;
}

// ---------------------------------------------------------------------------
// split-fp16 MFMA GEMM: Z = A @ W^T (split in/out). BK=32.
// R20: tile 64x64, 4 waves of 32x32, acc[2][2], counted-vmcnt pipeline
// (4 loads/tile). LDS 32KB. Grid = (N/64, M/64).
// ---------------------------------------------------------------------------
__global__ __launch_bounds__(256) void gemm_z(
    const _Float16* __restrict__ Ah, const _Float16* __restrict__ Al,
    const _Float16* __restrict__ Bh, const _Float16* __restrict__ Bl,
    _Float16* __restrict__ Zh, _Float16* __restrict__ Zl,
    int M, int N, int K) {
  __shared__ __align__(16) _Float16 AsH[2][64 * 32];
  __shared__ __align__(16) _Float16 AsL[2][64 * 32];
  __shared__ __align__(16) _Float16 BsH[2][64 * 32];
  __shared__ __align__(16) _Float16 BsL[2][64 * 32];
  int bx = blockIdx.x, by = blockIdx.y;
  swz8(bx, by);
  const int n0 = bx * 64, m0 = by * 64;
  const int tid = threadIdx.x;
  const int lane = tid & 63, wvi = tid >> 6;
  const int wm = (wvi >> 1) * 32, wn = (wvi & 1) * 32;
  const int l15 = lane & 15, quad = lane >> 4;
  // staging (R19-verified 64-row pattern): slot tid -> row tid>>2,
  // global seg (tid&3)^((row>>1)&3), LDS linear wvi*512 + lane*8.
  const int rS = tid >> 2;
  const int cS = ((tid & 3) ^ ((rS >> 1) & 3)) * 8;
  const int lbS = wvi * 512;
  const long gaS = (long)(m0 + rS) * K + cS;
  const long gbS = (long)(n0 + rS) * K + cS;
  f32x4 aM[2][2], aC[2][2];
#pragma unroll
  for (int i = 0; i < 2; i++)
#pragma unroll
    for (int j = 0; j < 2; j++) {
      aM[i][j] = (f32x4){0.f, 0.f, 0.f, 0.f};
      aC[i][j] = (f32x4){0.f, 0.f, 0.f, 0.f};
    }
  // prologue: issue tile 0 (no drain — iter 0's counted wait handles it)
  gld16(Ah + gaS, AsH[0] + lbS);
  gld16(Al + gaS, AsL[0] + lbS);
  gld16(Bh + gbS, BsH[0] + lbS);
  gld16(Bl + gbS, BsL[0] + lbS);
  int cur = 0;
  for (int k0 = 0; k0 < K; k0 += 32) {
    const int kn = k0 + 32;
    if (kn < K) {  // prefetch next tile, then wait only for CURRENT tile
      gld16(Ah + gaS + kn, AsH[cur ^ 1] + lbS);
      gld16(Al + gaS + kn, AsL[cur ^ 1] + lbS);
      gld16(Bh + gbS + kn, BsH[cur ^ 1] + lbS);
      gld16(Bl + gbS + kn, BsL[cur ^ 1] + lbS);
      vmwait<4>();
    } else {
      vmwait<0>();
    }
    __builtin_amdgcn_s_barrier();   // tile k complete in LDS (all waves)
    f16x8 fah[2], fal[2], fbh[2], fbl[2];
#pragma unroll
    for (int mi = 0; mi < 2; mi++) {
      int r = wm + mi * 16 + l15;
      int o = r * 32 + ((quad ^ ((r >> 1) & 3)) * 8);
      fah[mi] = *(const f16x8*)&AsH[cur][o];
      fal[mi] = *(const f16x8*)&AsL[cur][o];
    }
#pragma unroll
    for (int ni = 0; ni < 2; ni++) {
      int r = wn + ni * 16 + l15;
      int o = r * 32 + ((quad ^ ((r >> 1) & 3)) * 8);
      fbh[ni] = *(const f16x8*)&BsH[cur][o];
      fbl[ni] = *(const f16x8*)&BsL[cur][o];
    }
#pragma unroll
    for (int mi = 0; mi < 2; mi++)
#pragma unroll
      for (int ni = 0; ni < 2; ni++) {
        aM[mi][ni] = __builtin_amdgcn_mfma_f32_16x16x32_f16(
            fah[mi], fbh[ni], aM[mi][ni], 0, 0, 0);
        aC[mi][ni] = __builtin_amdgcn_mfma_f32_16x16x32_f16(
            fah[mi], fbl[ni], aC[mi][ni], 0, 0, 0);
        aC[mi][ni] = __builtin_amdgcn_mfma_f32_16x16x32_f16(
            fal[mi], fbh[ni], aC[mi][ni], 0, 0, 0);
      }
    __builtin_amdgcn_s_barrier();   // guard buf[cur] before next-iter overwrite
    cur ^= 1;
  }
#pragma unroll
  for (int mi = 0; mi < 2; mi++) {
    int rowg = m0 + wm + mi * 16 + quad * 4;
#pragma unroll
    for (int ni = 0; ni < 2; ni++) {
      int colg = n0 + wn + ni * 16 + l15;
#pragma unroll
      for (int rr = 0; rr < 4; rr++) {
        long off = (long)(rowg + rr) * N + colg;
        float z = aM[mi][ni][rr] + aC[mi][ni][rr] * (1.0f / 512.0f);
        _Float16 zh = (_Float16)z;
        Zh[off] = zh;
        Zl[off] = (_Float16)((z - (float)zh) * 512.0f);
      }
    }
  }
}

// ---------------------------------------------------------------------------
// split-fp16 MFMA Z.X^T + fused wrapped-diagonal mean reduce. BK=32.
// R18: counted-vmcnt pipeline. (128x128 geometry — diag math untouched.)
// ---------------------------------------------------------------------------
__global__ __launch_bounds__(256) void qkmv_hl(
    const _Float16* __restrict__ Zh, const _Float16* __restrict__ Zl,
    const _Float16* __restrict__ Xh, const _Float16* __restrict__ Xl,
    float* __restrict__ MV) {
  __shared__ __align__(16) _Float16 AsH[2][128 * 32];
  __shared__ __align__(16) _Float16 AsL[2][128 * 32];
  __shared__ __align__(16) _Float16 BsH[2][128 * 32];
  __shared__ __align__(16) _Float16 BsL[2][128 * 32];
  __shared__ float diag[255];
  const int bz = blockIdx.z;
  const long bb = (long)bz * LL * DD;
  const int n0 = blockIdx.x * 128, m0 = blockIdx.y * 128;
  const int tid = threadIdx.x;
  const int lane = tid & 63, wvi = tid >> 6;
  const int wm = (wvi >> 1) * 64, wn = (wvi & 1) * 64;
  const int l15 = lane & 15, quad = lane >> 4;
  const int ib = wvi * 128 + lane;
  const int r0 = ib >> 2, r1 = r0 + 16;
  const int c0 = ((ib & 3) ^ ((r0 >> 1) & 3)) * 8;
  const int c1 = ((ib & 3) ^ ((r1 >> 1) & 3)) * 8;
  const int lb0 = wvi * 1024, lb1 = wvi * 1024 + 512;
  const long ga0 = bb + (long)(m0 + r0) * DD + c0;
  const long ga1 = bb + (long)(m0 + r1) * DD + c1;
  const long gb0 = bb + (long)(n0 + r0) * DD + c0;
  const long gb1 = bb + (long)(n0 + r1) * DD + c1;
  if (tid < 255) diag[tid] = 0.0f;
  f32x4 aM[4][4], aC[4][4];
#pragma unroll
  for (int i = 0; i < 4; i++)
#pragma unroll
    for (int j = 0; j < 4; j++) {
      aM[i][j] = (f32x4){0.f, 0.f, 0.f, 0.f};
      aC[i][j] = (f32x4){0.f, 0.f, 0.f, 0.f};
    }
  // prologue: issue tile 0
  gld16(Zh + ga0, AsH[0] + lb0);
  gld16(Zh + ga1, AsH[0] + lb1);
  gld16(Zl + ga0, AsL[0] + lb0);
  gld16(Zl + ga1, AsL[0] + lb1);
  gld16(Xh + gb0, BsH[0] + lb0);
  gld16(Xh + gb1, BsH[0] + lb1);
  gld16(Xl + gb0, BsL[0] + lb0);
  gld16(Xl + gb1, BsL[0] + lb1);
  int cur = 0;
  for (int k0 = 0; k0 < DD; k0 += 32) {
    const int kn = k0 + 32;
    if (kn < DD) {
      gld16(Zh + ga0 + kn, AsH[cur ^ 1] + lb0);
      gld16(Zh + ga1 + kn, AsH[cur ^ 1] + lb1);
      gld16(Zl + ga0 + kn, AsL[cur ^ 1] + lb0);
      gld16(Zl + ga1 + kn, AsL[cur ^ 1] + lb1);
      gld16(Xh + gb0 + kn, BsH[cur ^ 1] + lb0);
      gld16(Xh + gb1 + kn, BsH[cur ^ 1] + lb1);
      gld16(Xl + gb0 + kn, BsL[cur ^ 1] + lb0);
      gld16(Xl + gb1 + kn, BsL[cur ^ 1] + lb1);
      vmwait<8>();
    } else {
      vmwait<0>();
    }
    __builtin_amdgcn_s_barrier();
    f16x8 fah[4], fal[4], fbh[4], fbl[4];
#pragma unroll
    for (int mi = 0; mi < 4; mi++) {
      int r = wm + mi * 16 + l15;
      int o = r * 32 + ((quad ^ ((r >> 1) & 3)) * 8);
      fah[mi] = *(const f16x8*)&AsH[cur][o];
      fal[mi] = *(const f16x8*)&AsL[cur][o];
    }
#pragma unroll
    for (int ni = 0; ni < 4; ni++) {
      int r = wn + ni * 16 + l15;
      int o = r * 32 + ((quad ^ ((r >> 1) & 3)) * 8);
      fbh[ni] = *(const f16x8*)&BsH[cur][o];
      fbl[ni] = *(const f16x8*)&BsL[cur][o];
    }
#pragma unroll
    for (int mi = 0; mi < 4; mi++)
#pragma unroll
      for (int ni = 0; ni < 4; ni++) {
        aM[mi][ni] = __builtin_amdgcn_mfma_f32_16x16x32_f16(
            fah[mi], fbh[ni], aM[mi][ni], 0, 0, 0);
        aC[mi][ni] = __builtin_amdgcn_mfma_f32_16x16x32_f16(
            fah[mi], fbl[ni], aC[mi][ni], 0, 0, 0);
        aC[mi][ni] = __builtin_amdgcn_mfma_f32_16x16x32_f16(
            fal[mi], fbh[ni], aC[mi][ni], 0, 0, 0);
      }
    __builtin_amdgcn_s_barrier();
    cur ^= 1;
  }
#pragma unroll
  for (int g = -3; g <= 3; g++) {
#pragma unroll
    for (int rr = 0; rr < 4; rr++) {
      float s = 0.0f;
#pragma unroll
      for (int mi = 0; mi < 4; mi++) {
        int ni = mi - g;
        if (ni >= 0 && ni < 4)
          s += aM[mi][ni][rr] + aC[mi][ni][rr] * (1.0f / 512.0f);
      }
      int d = 127 + (wm - wn) + g * 16 + quad * 4 + rr - l15;
      atomicAdd(&diag[d], s);
    }
  }
  __syncthreads();
  if (tid < 255) {
    int tau = (m0 - n0 + tid - 127 + LL) & (LL - 1);
    atomicAdd(&MV[(long)bz * LL + tau], diag[tid] * (1.0f / 512.0f));
  }
}

// ---------------------------------------------------------------------------
// fp16 MFMA GEMM: C[M,N] = act( A[M,K] @ W[N,K]^T + bias + R )
// R19: tile 128x64, waves 2x2 (64x32 each), BK=32, counted-vmcnt pipeline
// (3 loads/tile in flight). LDS 24KB. Grid = (N/64, M/128).
// FLAGS: 1=bias 2=gelu 4=residual 8=out-fp16
// ---------------------------------------------------------------------------
template <int FLAGS>
__global__ __launch_bounds__(256) void gemm_h(
    const _Float16* __restrict__ A, const _Float16* __restrict__ W,
    const void* __restrict__ biasBase, long bOff,
    const float* __restrict__ R, void* __restrict__ Cout,
    int M, int N, int K, const int* __restrict__ FLAG) {
  constexpr bool HAS_BIAS = (FLAGS & 1) != 0;
  constexpr bool DO_GELU = (FLAGS & 2) != 0;
  constexpr bool DO_RES = (FLAGS & 4) != 0;
  constexpr bool OUT_H = (FLAGS & 8) != 0;
  __shared__ __align__(16) _Float16 As[2][128 * 32];
  __shared__ __align__(16) _Float16 Bs[2][64 * 32];
  int bx = blockIdx.x, by = blockIdx.y;
  swz8(bx, by);
  const int n0 = bx * 64, m0 = by * 128;
  const int tid = threadIdx.x;
  const int lane = tid & 63, wvi = tid >> 6;
  const int wm = (wvi >> 1) * 64, wn = (wvi & 1) * 32;
  const int l15 = lane & 15, quad = lane >> 4;
  // A staging (identical to verified 128-row pattern): 2 gld16/thread
  const int ib = wvi * 128 + lane;
  const int r0 = ib >> 2, r1 = r0 + 16;
  const int c0 = ((ib & 3) ^ ((r0 >> 1) & 3)) * 8;
  const int c1 = ((ib & 3) ^ ((r1 >> 1) & 3)) * 8;
  const int lbA0 = wvi * 1024, lbA1 = wvi * 1024 + 512;
  const long ga0 = (long)(m0 + r0) * K + c0;
  const long ga1 = (long)(m0 + r1) * K + c1;
  // B staging: 64 rows, 256 slots (1 gld16/thread), same XOR-seg pattern
  const int jb = tid;
  const int rB = jb >> 2;
  const int cB = ((jb & 3) ^ ((rB >> 1) & 3)) * 8;
  const int lbB = wvi * 512;
  const long gb0 = (long)(n0 + rB) * K + cB;
  f32x4 acc[4][2];
#pragma unroll
  for (int i = 0; i < 4; i++)
#pragma unroll
    for (int j = 0; j < 2; j++) acc[i][j] = (f32x4){0.f, 0.f, 0.f, 0.f};
  // prologue: issue tile 0
  gld16(A + ga0, As[0] + lbA0);
  gld16(A + ga1, As[0] + lbA1);
  gld16(W + gb0, Bs[0] + lbB);
  int cur = 0;
  for (int k0 = 0; k0 < K; k0 += 32) {
    const int kn = k0 + 32;
    if (kn < K) {  // prefetch next tile, wait only for current
      gld16(A + ga0 + kn, As[cur ^ 1] + lbA0);
      gld16(A + ga1 + kn, As[cur ^ 1] + lbA1);
      gld16(W + gb0 + kn, Bs[cur ^ 1] + lbB);
      vmwait<3>();
    } else {
      vmwait<0>();
    }
    __builtin_amdgcn_s_barrier();
    f16x8 af[4], bfr[2];
#pragma unroll
    for (int mi = 0; mi < 4; mi++) {
      int r = wm + mi * 16 + l15;
      int o = r * 32 + ((quad ^ ((r >> 1) & 3)) * 8);
      af[mi] = *(const f16x8*)&As[cur][o];
    }
#pragma unroll
    for (int ni = 0; ni < 2; ni++) {
      int r = wn + ni * 16 + l15;
      int o = r * 32 + ((quad ^ ((r >> 1) & 3)) * 8);
      bfr[ni] = *(const f16x8*)&Bs[cur][o];
    }
#pragma unroll
    for (int mi = 0; mi < 4; mi++)
#pragma unroll
      for (int ni = 0; ni < 2; ni++)
        acc[mi][ni] = __builtin_amdgcn_mfma_f32_16x16x32_f16(
            af[mi], bfr[ni], acc[mi][ni], 0, 0, 0);
    __builtin_amdgcn_s_barrier();
    cur ^= 1;
  }
  float bcol[2];
  if constexpr (HAS_BIAS) {
    const int isf = *FLAG;
#pragma unroll
    for (int ni = 0; ni < 2; ni++)
      bcol[ni] = ldi(biasBase, bOff + n0 + wn + ni * 16 + l15, isf);
  }
#pragma unroll
  for (int mi = 0; mi < 4; mi++) {
    int rowg = m0 + wm + mi * 16 + quad * 4;
#pragma unroll
    for (int ni = 0; ni < 2; ni++) {
      int colg = n0 + wn + ni * 16 + l15;
#pragma unroll
      for (int rr = 0; rr < 4; rr++) {
        long off = (long)(rowg + rr) * N + colg;
        float v = acc[mi][ni][rr];
        if constexpr (HAS_BIAS) v += bcol[ni];
        if constexpr (DO_RES) v += R[off];
        if constexpr (DO_GELU) v = gelu_f(v);
        if constexpr (OUT_H) ((_Float16*)Cout)[off] = (_Float16)v;
        else ((float*)Cout)[off] = v;
      }
    }
  }
}

// ---------------------------------------------------------------------------
// top-6 of MV[b,:] + softmax.  grid (32), block 256
// ---------------------------------------------------------------------------
__global__ __launch_bounds__(256) void topk_k(const float* __restrict__ MV,
                                              float* __restrict__ WGT,
                                              int* __restrict__ DLY) {
  int b = blockIdx.x;
  __shared__ float vals[LL];
  __shared__ float rv[256];
  __shared__ int ri[256];
  __shared__ float selv[6];
  int tid = threadIdx.x;
  for (int i = tid; i < LL; i += 256) vals[i] = MV[(long)b * LL + i];
  __syncthreads();
  for (int it = 0; it < 6; it++) {
    float bv = -1e30f;
    int bi = LL - 1;
    for (int i = tid; i < LL; i += 256) {
      float v = vals[i];
      if (v > bv || (v == bv && i < bi)) { bv = v; bi = i; }
    }
    rv[tid] = bv; ri[tid] = bi;
    __syncthreads();
    for (int st = 128; st > 0; st >>= 1) {
      if (tid < st) {
        float ov = rv[tid + st]; int oi = ri[tid + st];
        if (ov > rv[tid] || (ov == rv[tid] && oi < ri[tid])) {
          rv[tid] = ov; ri[tid] = oi;
        }
      }
      __syncthreads();
    }
    if (tid == 0) {
      selv[it] = rv[0];
      DLY[b * 6 + it] = ri[0];
      vals[ri[0]] = -1e30f;
    }
    __syncthreads();
  }
  if (tid == 0) {
    float mx = selv[0];
    float e[6], s = 0.0f;
    for (int i = 0; i < 6; i++) { e[i] = expf(selv[i] - mx); s += e[i]; }
    for (int i = 0; i < 6; i++) WGT[b * 6 + i] = e[i] / s;
  }
}

// ---------------------------------------------------------------------------
// time-delay aggregation, fp16 in/out (chunk-local): grid (1024, NB), block 128
// ---------------------------------------------------------------------------
__global__ __launch_bounds__(128) void agg_k(const _Float16* __restrict__ V,
                                             const float* __restrict__ WGT,
                                             const int* __restrict__ DLY,
                                             _Float16* __restrict__ O) {
  int l = blockIdx.x, b = blockIdx.y;
  int tid = threadIdx.x;
  float w[6]; int dl[6];
#pragma unroll
  for (int i = 0; i < 6; i++) { w[i] = WGT[b * 6 + i]; dl[i] = DLY[b * 6 + i]; }
  long base = (long)b * LL * DD;
  int d = tid * 4;
  float a0 = 0, a1 = 0, a2 = 0, a3 = 0;
#pragma unroll
  for (int i = 0; i < 6; i++) {
    int row = (l + dl[i]) & (LL - 1);
    H4 t; t.u = *(const uint2*)&V[base + (long)row * DD + d];
    a0 += w[i] * (float)t.h[0];
    a1 += w[i] * (float)t.h[1];
    a2 += w[i] * (float)t.h[2];
    a3 += w[i] * (float)t.h[3];
  }
  H4 r;
  r.h[0] = (_Float16)a0; r.h[1] = (_Float16)a1;
  r.h[2] = (_Float16)a2; r.h[3] = (_Float16)a3;
  *(uint2*)&O[base + (long)l * DD + d] = r.u;
}

// ---------------------------------------------------------------------------
// series_decomp residual (f32 out only, race-free). grid (2, 16, 32), block 256
// ---------------------------------------------------------------------------
__global__ __launch_bounds__(256) void decomp_k(const float* __restrict__ Xin,
                                                float* __restrict__ Out) {
  int d = blockIdx.x * 256 + threadIdx.x;
  int l0 = blockIdx.y * 64;
  int b = blockIdx.z;
  const float* xb = Xin + (long)b * LL * DD + d;
  float* ob = Out + (long)b * LL * DD + d;
  float wsum = 0.0f;
  for (int j = l0 - 12; j <= l0 + 12; j++) {
    int jj = min(max(j, 0), LL - 1);
    wsum += xb[(long)jj * DD];
  }
  for (int l = l0; l < l0 + 64; l++) {
    float xv = xb[(long)l * DD];
    ob[(long)l * DD] = xv - wsum * (1.0f / 25.0f);
    int ja = min(l + 13, LL - 1);
    int jr = max(l - 12, 0);
    wsum += xb[(long)ja * DD] - xb[(long)jr * DD];
  }
}

// special layernorm. grid (1024,32), block 256
__global__ __launch_bounds__(256) void ln_k(const float* __restrict__ X,
                                            const void* __restrict__ g,
                                            const void* __restrict__ be,
                                            float* __restrict__ XHo,
                                            const int* __restrict__ FLAG) {
  const int isf = *FLAG;
  int l = blockIdx.x, b = blockIdx.y;
  const float* xr = X + ((long)b * LL + l) * DD;
  int tid = threadIdx.x;
  float x0 = xr[tid], x1 = xr[tid + 256];
  __shared__ float rs[256], rq[256];
  rs[tid] = x0 + x1;
  rq[tid] = x0 * x0 + x1 * x1;
  __syncthreads();
  for (int st = 128; st > 0; st >>= 1) {
    if (tid < st) { rs[tid] += rs[tid + st]; rq[tid] += rq[tid + st]; }
    __syncthreads();
  }
  float mu = rs[0] * (1.0f / 512.0f);
  float var = rq[0] * (1.0f / 512.0f) - mu * mu;
  float rstd = rsqrtf(var + 1e-5f);
  float* o = XHo + ((long)b * LL + l) * DD;
  o[tid] = (x0 - mu) * rstd * ldi(g, tid, isf) + ldi(be, tid, isf);
  o[tid + 256] = (x1 - mu) * rstd * ldi(g, tid + 256, isf) + ldi(be, tid + 256, isf);
}

// column-mean partials. grid (2, 8, 32), block 256: part sums 128 rows.
__global__ __launch_bounds__(256) void colmean_k(const float* __restrict__ XHo,
                                                 float* __restrict__ CMp) {
  int d = blockIdx.x * 256 + threadIdx.x;
  int part = blockIdx.y;
  int b = blockIdx.z;
  const float* p = XHo + (long)b * LL * DD + (long)part * 128 * DD + d;
  float s = 0.0f;
  for (int l = 0; l < 128; l++) s += p[(long)l * DD];
  CMp[((long)part * BB + b) * DD + d] = s;
}

// OUT = gelu(XH - mean) * mark. grid (1024,32), block 256
__global__ __launch_bounds__(256) void geluout_k(const float* __restrict__ XHo,
                                                 const float* __restrict__ CMp,
                                                 const void* __restrict__ mark,
                                                 float* __restrict__ OUT,
                                                 const int* __restrict__ FLAG) {
  const int isf = *FLAG;
  int l = blockIdx.x, b = blockIdx.y;
  int tid = threadIdx.x;
  float mk = ldi(mark, (long)b * LL + l, isf);
  long off = ((long)b * LL + l) * DD;
#pragma unroll
  for (int h = 0; h < 2; h++) {
    int d = tid + h * 256;
    float cs = 0.0f;
#pragma unroll
    for (int p = 0; p < 8; p++) cs += CMp[((long)p * BB + b) * DD + d];
    float v = XHo[off + d] - cs * (1.0f / 1024.0f);
    OUT[off + d] = gelu_f(v) * mk;
  }
}

// ---------------------------------------------------------------------------
// proj stage 1 v2: read-once split-K. grid (512), block 256.
// ---------------------------------------------------------------------------
__global__ __launch_bounds__(256) void proj1_k(const float* __restrict__ OUT,
                                               const void* __restrict__ Wp,
                                               float* __restrict__ PB2,
                                               const int* __restrict__ FLAG) {
  const int isf = *FLAG;
  const int blk = blockIdx.x;
  const int tid = threadIdx.x;
  const int wave = tid >> 6, lane = tid & 63;
  const int grp = lane >> 4, ln = lane & 15;
  const long e = (long)blk * 1024 + tid * 4;
  float w[10][4];
  if (isf) {
    const float* wp = (const float*)Wp;
#pragma unroll
    for (int n = 0; n < 10; n++) {
      float4 t = *(const float4*)&wp[(long)n * 524288 + e];
      w[n][0] = t.x; w[n][1] = t.y; w[n][2] = t.z; w[n][3] = t.w;
    }
  } else {
    const u16* wp = (const u16*)Wp;
#pragma unroll
    for (int n = 0; n < 10; n++) {
      uint2 u = *(const uint2*)&wp[(long)n * 524288 + e];
      w[n][0] = bf2f((u16)(u.x & 0xffff));
      w[n][1] = bf2f((u16)(u.x >> 16));
      w[n][2] = bf2f((u16)(u.y & 0xffff));
      w[n][3] = bf2f((u16)(u.y >> 16));
    }
  }
  __shared__ float sm[4][4][BB][16];  // [wave][grp][b][n] = 32 KB
  float4 xn = *(const float4*)&OUT[e];  // prefetch b=0
  for (int b = 0; b < BB; b++) {
    float4 x = xn;
    if (b < BB - 1) xn = *(const float4*)&OUT[(long)(b + 1) * 524288 + e];
    float acc[10];
#pragma unroll
    for (int n = 0; n < 10; n++)
      acc[n] = x.x * w[n][0] + x.y * w[n][1] + x.z * w[n][2] + x.w * w[n][3];
#pragma unroll
    for (int s = 1; s <= 8; s <<= 1)
#pragma unroll
      for (int n = 0; n < 10; n++) acc[n] += __shfl_xor(acc[n], s, 64);
    float v = 0.0f;
#pragma unroll
    for (int n = 0; n < 10; n++) v = (ln == n) ? acc[n] : v;
    if (ln < 10) sm[wave][grp][b][ln] = v;
  }
  __syncthreads();
  for (int o = tid; o < BB * 10; o += 256) {
    int b = o / 10, n = o - b * 10;
    float s = 0.0f;
#pragma unroll
    for (int w4 = 0; w4 < 4; w4++)
#pragma unroll
      for (int g = 0; g < 4; g++) s += sm[w4][g][b][n];
    PB2[(long)o * 512 + blk] = s;
  }
}

// proj stage 2 v2: reduce 512 partials per (b,n). grid (10,32), block 64
__global__ __launch_bounds__(64) void proj2_k(const float* __restrict__ PB2,
                                              const void* __restrict__ bp,
                                              void* __restrict__ out,
                                              const int* __restrict__ FLAG) {
  const int isf = *FLAG;
  int n = blockIdx.x, b = blockIdx.y;
  int o = b * 10 + n;
  int tid = threadIdx.x;
  float s = 0.0f;
  for (int j = tid; j < 512; j += 64) s += PB2[(long)o * 512 + j];
#pragma unroll
  for (int st = 32; st > 0; st >>= 1) s += __shfl_xor(s, st, 64);
  if (tid == 0) {
    s += ldi(bp, n, isf);
    if (isf) ((float*)out)[o] = s;
    else ((u16*)out)[o] = f2bf(s);
  }
}

// ---------------------------------------------------------------------------
extern "C" void kernel_launch(void* const* d_in, const int* in_sizes, int n_in,
                              void* d_out, int out_size, void* d_ws, size_t ws_size,
                              hipStream_t stream) {
  const void* xe = d_in[0];
  const void* mark = d_in[1];
  const void* cw = d_in[2];
  const void* Wq = d_in[3];
  const void* Wk = d_in[5];
  const void* Wv = d_in[7];
  const void* bv = d_in[8];
  const void* Wo = d_in[9];
  const void* bo = d_in[10];
  const void* Wff1 = d_in[11];
  const void* Wff2 = d_in[12];
  const void* lng = d_in[13];
  const void* lnb = d_in[14];
  const void* Wp = d_in[15];
  const void* bp = d_in[16];

  char* ws = (char*)d_ws;
  float* X      = (float*)(ws + 0L);               // 64 MiB f32 residual
  _Float16* XH  = (_Float16*)(ws + 67108864L);     // fp16 X-high, 32 MiB
  _Float16* XL  = (_Float16*)(ws + 100663296L);    // fp16 X-low*512 / AGh
  _Float16* AGh = (_Float16*)(ws + 100663296L);
  _Float16* ZH  = (_Float16*)(ws + 134217728L);    // Z-high chunk, 4 MiB
  _Float16* ZL  = (_Float16*)(ws + 138412032L);    // Z-low chunk, 4 MiB
  _Float16* Ph  = (_Float16*)(ws + 134217728L);    // Phase B: 8 MiB chunk
  float* CMp    = (float*)(ws + 134217728L);       // final: colmean partials
  float* wT     = (float*)(ws + 142606336L);       // conv wT (dead after embed)
  // Phase A overlays (all dead by Phase B):
  _Float16* KTH = (_Float16*)(ws + 142606336L);    // Wk^T split hi, 0.5 MiB
  _Float16* KTL = (_Float16*)(ws + 143130624L);    // Wk^T split lo
  _Float16* QTH = (_Float16*)(ws + 143654912L);    // Wq^T split hi
  _Float16* QTL = (_Float16*)(ws + 144179200L);    // Wq^T split lo
  _Float16* GH  = (_Float16*)(ws + 144703488L);    // G split hi, 0.5 MiB
  _Float16* GL  = (_Float16*)(ws + 145227776L);    // G split lo
  // Phase B overlays:
  _Float16* Wvh = (_Float16*)(ws + 142606336L);
  _Float16* Woh = (_Float16*)(ws + 143130624L);
  _Float16* W1h = (_Float16*)(ws + 143654912L);    // 2 MiB
  _Float16* W2h = (_Float16*)(ws + 145752064L);    // 2 MiB
  float* MV  = (float*)(ws + 147849216L);
  float* WGT = (float*)(ws + 147980288L);
  int*   DLY = (int*)(ws + 147981312L);
  int*  FLAG = (int*)(ws + 148068352L);
  float* S2  = (float*)(ws + 67108864L);           // FFN f32 (spans XH+XL)
  float* PB2 = (float*)(ws + 67108864L);           // proj partials (S2 dead)
  _Float16* Hb = (_Float16*)X;                     // FFN hidden (X dead)

  const long AD = (long)LL * DD;   // 524288
  const int M = BB * LL;           // 32768

  detect_k<<<1, 64, 0, stream>>>((const uint32_t*)mark, FLAG);
  wT_k<<<126, 256, 0, stream>>>(cw, wT, FLAG);
  conv_embed_k<<<dim3(64, 32), 256, 0, stream>>>(xe, wT, X, XH, XL, FLAG);

  for (int l = 0; l < 3; l++) {
    const long oW = (long)l * DD * DD;
    const long oB = (long)l * DD;
    const long oF = (long)l * DFF * DD;

    // ---- Phase A: delay selection via G-trick + fp16x2 split MFMA ----
    tsplit2_k<<<dim3(8, 8, 2), 256, 0, stream>>>(Wk, Wq, oW,
                                                 KTH, KTL, QTH, QTL, FLAG);
    gemm_z<<<dim3(8, 8), 256, 0, stream>>>(KTH, KTL, QTH, QTL,
                                           GH, GL, 512, 512, 512);
    hipMemsetAsync(MV, 0, (long)BB * LL * sizeof(float), stream);
    for (int cb = 0; cb < 8; cb++) {
      const long co = (long)cb * 4 * AD;
      gemm_z<<<dim3(8, 64), 256, 0, stream>>>(
          XH + co, XL + co, GH, GL, ZH, ZL, 4096, DD, DD);
      qkmv_hl<<<dim3(8, 8, 4), 256, 0, stream>>>(
          ZH, ZL, XH + co, XL + co, MV + (long)cb * 4 * LL);
    }
    topk_k<<<32, 256, 0, stream>>>(MV, WGT, DLY);

    // ---- Phase B: fp16 MFMA for V / agg / Wo / FFN ----
    wcvt6_k<<<1280, 256, 0, stream>>>(Wv, Wo, Wff1, Wff2, oW, oF,
                                      Wvh, Woh, W1h, W2h, FLAG);

    // V (fp16) per 8-batch chunk -> Ph (over ZH/ZL, dead), agg -> AGh
    for (int cb = 0; cb < 4; cb++) {
      const _Float16* xh = XH + (long)cb * 8 * AD;
      gemm_h<1 | 8><<<dim3(8, 64), 256, 0, stream>>>(
          xh, Wvh, bv, oB, nullptr, Ph, 8192, DD, DD, FLAG);
      agg_k<<<dim3(1024, 8), 128, 0, stream>>>(
          Ph, WGT + cb * 48, DLY + cb * 48, AGh + (long)cb * 8 * AD);
    }

    // X = X + AGh @ Wo^T + bo (full M, in-place residual)
    gemm_h<1 | 4><<<dim3(8, 256), 256, 0, stream>>>(
        AGh, Woh, bo, oB, X, X, M, DD, DD, FLAG);

    // x = decomp(X) -> S2 f32 (over XH/XL, both dead)
    decomp_k<<<dim3(2, 16, 32), 256, 0, stream>>>(X, S2);

    // FFN per 8-batch chunk: S2 chunk -> fp16 Ph; hidden -> Hb (X region);
    // S2chunk = S2chunk + (gelu-hidden) @ W2^T
    for (int cb = 0; cb < 4; cb++) {
      float* xd = S2 + (long)cb * 8 * AD;
      acvt_k<<<2048, 256, 0, stream>>>(xd, Ph, 4194304);
      gemm_h<2 | 8><<<dim3(32, 64), 256, 0, stream>>>(
          Ph, W1h, nullptr, 0, nullptr, Hb, 8192, DFF, DD, FLAG);
      gemm_h<4><<<dim3(8, 64), 256, 0, stream>>>(
          Hb, W2h, nullptr, 0, xd, xd, 8192, DD, DFF, FLAG);
    }

    // x = decomp(S2) -> X; then split X -> (XH, XL) for next layer
    decomp_k<<<dim3(2, 16, 32), 256, 0, stream>>>(S2, X);
    if (l < 2) split_k<<<8192, 256, 0, stream>>>(X, XH, XL, 16777216);
  }

  // final special layernorm + gelu + mask + projection
  ln_k<<<dim3(1024, 32), 256, 0, stream>>>(X, lng, lnb, S2, FLAG);
  colmean_k<<<dim3(2, 8, 32), 256, 0, stream>>>(S2, CMp);
  geluout_k<<<dim3(1024, 32), 256, 0, stream>>>(S2, CMp, mark, X, FLAG);
  proj1_k<<<512, 256, 0, stream>>>(X, Wp, PB2, FLAG);
  proj2_k<<<dim3(10, 32), 64, 0, stream>>>(PB2, bp, d_out, FLAG);
}